// Round 7
// baseline (1299.166 us; speedup 1.0000x reference)
//
#include <hip/hip_runtime.h>
#include <stdint.h>

// ---------------------------------------------------------------------------
// LocalDino forward on MI355X (gfx950).
// Inputs: float32. OUTPUT: float32 (reference dtype). Internal: bf16 + f32 acc.
// Heavy math via mfma_f32_16x16x32_bf16. gemm_bt and conv_gemm use:
//   - triple-buffered counted-vmcnt software pipeline
//   - conflict-free XOR-swizzled LDS (R2 verified conflicts -> 0)
//   - SPLIT-K (R3: latency-bound at 1 block/CU; fix = more blocks/CU)
//   - conv K-tile iteration permuted ci-chunk-outer/tap-inner (R6: fetch
//     274->82 MB) and NOW fully compile-time (R6: VALUBusy 44% = per-phase
//     im2col address math; template<L2W,L2C,NK> + 9-unrolled taps + 18
//     precomputed tap pointers cut it to ~1 add per load).
// Decoder workspace layout is the R3-verified one; partials in audited
// dead regions. conv grid keeps M on blockIdx.x (XCD A-panel sharing).
// ---------------------------------------------------------------------------

typedef unsigned short u16;
typedef __bf16 bf16x8 __attribute__((ext_vector_type(8)));
typedef short  s16x8  __attribute__((ext_vector_type(8)));
typedef float  f32x4  __attribute__((ext_vector_type(4)));

__device__ __forceinline__ float b2f(u16 x) { return __uint_as_float(((unsigned)x) << 16); }
__device__ __forceinline__ u16 f2b(float f) {
  unsigned u = __float_as_uint(f);
  unsigned r = (u + 0x7fffu + ((u >> 16) & 1u)) >> 16;   // RNE
  return (u16)r;
}
__device__ __forceinline__ void async16(u16* lds, const u16* g) {
  __builtin_amdgcn_global_load_lds((const __attribute__((address_space(1))) void*)g,
                                   (__attribute__((address_space(3))) void*)lds, 16, 0, 0);
}
__device__ __forceinline__ float gelu_f(float x) {
  return 0.5f * x * (1.0f + erff(x * 0.70710678118654752f));  // exact gelu
}

// f32 -> bf16 canonicalization
__global__ __launch_bounds__(256) void cvt_f2b(const float* __restrict__ src,
                                               u16* __restrict__ dst, int n) {
  const int i = (blockIdx.x * 256 + threadIdx.x) * 4;
  if (i + 3 < n) {
    const float4 v = *(const float4*)(src + i);
    dst[i] = f2b(v.x); dst[i + 1] = f2b(v.y); dst[i + 2] = f2b(v.z); dst[i + 3] = f2b(v.w);
  }
}

// ---------------------------------------------------------------------------
// bf16 GEMM: C[m,n] = sum_k A[m,k]*B[n,k] (+bias[n]) (+gelu). Cb bf16 output.
// Batched via blockIdx.z: off = (z/ZH)*s?b + (z%ZH)*s?h.
// SPLIT-K mode: Part != nullptr -> blockIdx.z = k-slice (ZH must be 1).
// ---------------------------------------------------------------------------
__global__ __launch_bounds__(256) void gemm_bt(
    const u16* __restrict__ A, int lda, long long sAb, long long sAh,
    const u16* __restrict__ B, int ldb, long long sBb, long long sBh,
    u16* __restrict__ Cb, int ldc, long long sCb, long long sCh,
    const float* __restrict__ bias, int epi, int ZH, int nk,
    float* __restrict__ Part)
{
  __shared__ u16 As[3][128 * 32];
  __shared__ u16 Bs[3][128 * 32];
  const int tid = threadIdx.x;
  const int zb = blockIdx.z / ZH, zh = blockIdx.z % ZH;
  const u16* Ab = A + zb * sAb + zh * sAh;
  const u16* Bb = B + zb * sBb + zh * sBh;
  const int m0 = blockIdx.y << 7, n0 = blockIdx.x << 7;
  const int wave = tid >> 6, lane = tid & 63;
  const int wm = (wave >> 1) << 6, wn = (wave & 1) << 6;
  const int lr = lane & 15, lq = lane >> 4;
  const int rowb = tid >> 2;
  const int koff = Part ? (zb * (nk << 5)) : 0;   // k-slice element offset
  const int kc_e = (((tid & 3) ^ ((tid >> 3) & 3)) << 3);
  const int kslot = ((lq ^ ((lr >> 1) & 3)) << 3);

  const u16* Arow0 = Ab + (long long)(m0 + rowb)      * lda + kc_e + koff;
  const u16* Arow1 = Ab + (long long)(m0 + rowb + 64) * lda + kc_e + koff;
  const u16* Brow0 = Bb + (long long)(n0 + rowb)      * ldb + kc_e + koff;
  const u16* Brow1 = Bb + (long long)(n0 + rowb + 64) * ldb + kc_e + koff;

  f32x4 acc[4][4] = {};

  auto stage = [&](int kt, int b) {
    const int k0 = kt << 5;
    async16(&As[b][tid * 8],         Arow0 + k0);
    async16(&As[b][(tid + 256) * 8], Arow1 + k0);
    async16(&Bs[b][tid * 8],         Brow0 + k0);
    async16(&Bs[b][(tid + 256) * 8], Brow1 + k0);
  };

  stage(0, 0);
  if (nk > 1) stage(1, 1);
  int cur = 0;
  for (int kt = 0; kt < nk; ++kt) {
    if (kt + 2 < nk) {
      int nb = cur + 2; if (nb >= 3) nb -= 3;
      stage(kt + 2, nb);
      asm volatile("s_waitcnt vmcnt(8)" ::: "memory");
    } else if (kt + 1 < nk) {
      asm volatile("s_waitcnt vmcnt(4)" ::: "memory");
    } else {
      asm volatile("s_waitcnt vmcnt(0)" ::: "memory");
    }
    asm volatile("s_barrier" ::: "memory");   // publish tile kt to all waves

    bf16x8 af[4], bfv[4];
#pragma unroll
    for (int mi = 0; mi < 4; ++mi)
      af[mi] = __builtin_bit_cast(bf16x8, *(const s16x8*)&As[cur][((wm + mi * 16 + lr) << 5) + kslot]);
#pragma unroll
    for (int ni = 0; ni < 4; ++ni)
      bfv[ni] = __builtin_bit_cast(bf16x8, *(const s16x8*)&Bs[cur][((wn + ni * 16 + lr) << 5) + kslot]);
#pragma unroll
    for (int mi = 0; mi < 4; ++mi)
#pragma unroll
      for (int ni = 0; ni < 4; ++ni)
        acc[mi][ni] = __builtin_amdgcn_mfma_f32_16x16x32_bf16(af[mi], bfv[ni], acc[mi][ni], 0, 0, 0);

    asm volatile("s_barrier" ::: "memory");   // protect buffer cur
    ++cur; if (cur == 3) cur = 0;
  }

  if (Part) {
    float* P = Part + (long long)zb * sCb;
#pragma unroll
    for (int ni = 0; ni < 4; ++ni) {
      const int col = n0 + wn + ni * 16 + lr;
#pragma unroll
      for (int mi = 0; mi < 4; ++mi) {
        const int row0 = m0 + wm + mi * 16 + (lq << 2);
#pragma unroll
        for (int r = 0; r < 4; ++r)
          P[(long long)(row0 + r) * ldc + col] = acc[mi][ni][r];
      }
    }
    return;
  }

  const long long Co = zb * sCb + zh * sCh;
#pragma unroll
  for (int ni = 0; ni < 4; ++ni) {
    const int col = n0 + wn + ni * 16 + lr;
    const float badd = bias ? bias[col] : 0.0f;
#pragma unroll
    for (int mi = 0; mi < 4; ++mi) {
      const int row0 = m0 + wm + mi * 16 + (lq << 2);
#pragma unroll
      for (int r = 0; r < 4; ++r) {
        float v = acc[mi][ni][r] + badd;
        if (epi == 1) v = gelu_f(v);
        Cb[Co + (long long)(row0 + r) * ldc + col] = f2b(v);
      }
    }
  }
}

// sum S f32 partial planes + bias -> bf16. N pow2. 4 elems/thread.
__global__ __launch_bounds__(256) void reduce_bias(
    const float* __restrict__ Part, long long sPart, int S,
    const float* __restrict__ bias, int N,
    u16* __restrict__ Out, long long total)
{
  const long long i = ((long long)blockIdx.x * 256 + threadIdx.x) * 4;
  if (i >= total) return;
  f32x4 s = *(const f32x4*)(Part + i);
  for (int p = 1; p < S; ++p) {
    const f32x4 v = *(const f32x4*)(Part + (long long)p * sPart + i);
    s[0] += v[0]; s[1] += v[1]; s[2] += v[2]; s[3] += v[3];
  }
  const int colb = (int)(i & (N - 1));
#pragma unroll
  for (int j = 0; j < 4; ++j)
    Out[i + j] = f2b(s[j] + bias[colb + j]);
}

// sum S f32 partial planes + conv-bias + BN(eval) + ReLU -> bf16 NHWC.
__global__ __launch_bounds__(256) void reduce_bn(
    const float* __restrict__ Part, long long sPart, int S,
    const float* __restrict__ bn_g, const float* __restrict__ bn_b,
    const float* __restrict__ bn_m, const float* __restrict__ bn_v,
    const float* __restrict__ cb, int Cout,
    u16* __restrict__ Out, long long total)
{
  const long long i = ((long long)blockIdx.x * 256 + threadIdx.x) * 4;
  if (i >= total) return;
  f32x4 s = *(const f32x4*)(Part + i);
  for (int p = 1; p < S; ++p) {
    const f32x4 v = *(const f32x4*)(Part + (long long)p * sPart + i);
    s[0] += v[0]; s[1] += v[1]; s[2] += v[2]; s[3] += v[3];
  }
  const int colb = (int)(i & (Cout - 1));
#pragma unroll
  for (int j = 0; j < 4; ++j) {
    const int col = colb + j;
    const float inv = rsqrtf(bn_v[col] + 1e-5f);
    const float bs = bn_g[col] * inv;
    const float bsh = (cb[col] - bn_m[col]) * bs + bn_b[col];
    Out[i + j] = f2b(fmaxf(s[j] * bs + bsh, 0.0f));
  }
}

// ---------------------------------------------------------------------------
// Implicit-GEMM conv3x3 SAME, NHWC bf16 in, fused BN(eval)+ReLU, bf16 out.
// K = 9*Cin as (tap*Cin + ci). Wr: [Npad x K] bf16. Tile 128(M on x) x 64(N).
// Compile-time template <L2W, L2C, NK>: H=W=1<<L2W, Cin=1<<L2C, NK phases
// per slice. Iteration ci-chunk-outer / tap-inner; tap (and LDS buffer
// index = tap%3, and tap<<L2C) are compile-time via the 9-unrolled loop.
// 18 tap pointers precomputed once; invalid taps -> 4 KB zero page (holds
// >= 2*Cin zero bytes so +ci offsets stay inside). Per-phase address math
// = one +ciOff add per load. Triple-buffered counted-vmcnt pipeline +
// XOR-swizzled LDS; numerics identical to the R6 kernel.
// ---------------------------------------------------------------------------
template <int L2W, int L2C, int NK>
__global__ __launch_bounds__(256) void conv_gemm(
    const u16* __restrict__ U, const u16* __restrict__ Wr,
    u16* __restrict__ Out,
    const float* __restrict__ bn_g, const float* __restrict__ bn_b,
    const float* __restrict__ bn_m, const float* __restrict__ bn_v,
    const float* __restrict__ cb,
    const u16* __restrict__ zpg,
    int CoutReal,
    float* __restrict__ Part, long long sPart)
{
  constexpr int L2HW = 2 * L2W;
  constexpr int HH = 1 << L2W;          // H == W for all decoder convs
  constexpr int Kdim = 9 << L2C;
  constexpr int OD = NK / 9;            // ci-chunk iterations per slice
  __shared__ u16 As[3][128 * 32];       // 8 KB per buffer
  __shared__ u16 Bs[3][64 * 32];        // 4 KB per buffer
  const int tid = threadIdx.x;
  const int m0 = blockIdx.x << 7, n0 = blockIdx.y << 6;   // M on x (XCD share)
  const int slice = blockIdx.z;
  const int gdbase = slice * OD;        // starting global ci-chunk
  const int wave = tid >> 6, lane = tid & 63;
  const int wm = (wave >> 1) << 6, wn = (wave & 1) << 5;
  const int lr = lane & 15, lq = lane >> 4;
  const int rowb = tid >> 2;
  const int kc_e = (((tid & 3) ^ ((tid >> 3) & 3)) << 3);
  const int kslot = ((lq ^ ((lr >> 1) & 3)) << 3);
  const int ciStart = (gdbase << 5) + kc_e;   // element offset, < Cin

  // 18 precomputed tap pointers (ciStart folded in).
  const u16* Pt[2][9];
#pragma unroll
  for (int i = 0; i < 2; ++i) {
    const int mrow = m0 + rowb + (i << 6);
    const int img = mrow >> L2HW;
    const int rem = mrow & ((1 << L2HW) - 1);
    const int y = rem >> L2W, x = rem & (HH - 1);
    const long long ibase = (long long)img << L2HW;
#pragma unroll
    for (int tap = 0; tap < 9; ++tap) {
      const int dy = tap / 3, dx = tap % 3;
      const int yy = y + dy - 1, xx = x + dx - 1;
      Pt[i][tap] = ((unsigned)yy < (unsigned)HH && (unsigned)xx < (unsigned)HH)
          ? U + ((((ibase + (yy << L2W) + xx)) << L2C) + ciStart)
          : zpg + ciStart;
    }
  }
  const u16* Bp = Wr + (long long)(n0 + rowb) * Kdim + kc_e + (gdbase << 5);

  f32x4 acc[4][2] = {};

#define STAGE(TAP, CIE, B)                                                 \
  do {                                                                    \
    async16(&As[(B)][tid * 8],         Pt[0][(TAP)] + (CIE));             \
    async16(&As[(B)][(tid + 256) * 8], Pt[1][(TAP)] + (CIE));             \
    async16(&Bs[(B)][tid * 8],         Bp + (CIE) + ((TAP) << L2C));      \
  } while (0)

#define COMPUTE(B)                                                         \
  do {                                                                    \
    bf16x8 af[4], bfv[2];                                                 \
    _Pragma("unroll") for (int mi = 0; mi < 4; ++mi)                      \
      af[mi] = __builtin_bit_cast(bf16x8,                                 \
        *(const s16x8*)&As[(B)][((wm + mi * 16 + lr) << 5) + kslot]);     \
    _Pragma("unroll") for (int ni = 0; ni < 2; ++ni)                      \
      bfv[ni] = __builtin_bit_cast(bf16x8,                                \
        *(const s16x8*)&Bs[(B)][((wn + ni * 16 + lr) << 5) + kslot]);     \
    _Pragma("unroll") for (int mi = 0; mi < 4; ++mi)                      \
      _Pragma("unroll") for (int ni = 0; ni < 2; ++ni)                    \
        acc[mi][ni] = __builtin_amdgcn_mfma_f32_16x16x32_bf16(            \
            af[mi], bfv[ni], acc[mi][ni], 0, 0, 0);                       \
  } while (0)

  // Prologue: phases 0,1 (od=0, taps 0,1) in flight (6 loads/thread).
  STAGE(0, 0, 0);
  STAGE(1, 0, 1);

  int ciOff = 0;
  for (int od = 0; od < OD - 1; ++od, ciOff += 32) {
#pragma unroll
    for (int tap = 0; tap < 9; ++tap) {
      // Stage phase+2 (wraps into next ci-chunk for taps 7,8). Buffer
      // (tap+2)%3 was last read at phase-1; the trailing barrier of that
      // phase ordered its ds_reads before this overwrite.
      if (tap < 7) STAGE(tap + 2, ciOff, (tap + 2) % 3);
      else         STAGE(tap - 7, ciOff + 32, (tap + 2) % 3);
      asm volatile("s_waitcnt vmcnt(6)" ::: "memory");
      asm volatile("s_barrier" ::: "memory");   // publish current phase
      COMPUTE(tap % 3);
      asm volatile("s_barrier" ::: "memory");   // protect current buffer
    }
  }
  // Epilogue ci-chunk (od = OD-1): drain the pipeline.
#pragma unroll
  for (int tap = 0; tap < 9; ++tap) {
    if (tap < 7) {
      STAGE(tap + 2, ciOff, (tap + 2) % 3);
      asm volatile("s_waitcnt vmcnt(6)" ::: "memory");
    } else if (tap == 7) {
      asm volatile("s_waitcnt vmcnt(3)" ::: "memory");
    } else {
      asm volatile("s_waitcnt vmcnt(0)" ::: "memory");
    }
    asm volatile("s_barrier" ::: "memory");
    COMPUTE(tap % 3);
    asm volatile("s_barrier" ::: "memory");
  }
#undef STAGE
#undef COMPUTE

  if (Part) {
    float* P = Part + (long long)slice * sPart;
#pragma unroll
    for (int ni = 0; ni < 2; ++ni) {
      const int col = n0 + wn + ni * 16 + lr;
#pragma unroll
      for (int mi = 0; mi < 4; ++mi) {
        const int row0 = m0 + wm + mi * 16 + (lq << 2);
#pragma unroll
        for (int r = 0; r < 4; ++r)
          P[(long long)(row0 + r) * CoutReal + col] = acc[mi][ni][r];
      }
    }
    return;
  }

#pragma unroll
  for (int ni = 0; ni < 2; ++ni) {
    const int col = n0 + wn + ni * 16 + lr;
    const bool ok = col < CoutReal;
    float bs = 0.0f, bsh = 0.0f;
    if (ok) {
      const float inv = rsqrtf(bn_v[col] + 1e-5f);
      bs = bn_g[col] * inv;
      bsh = (cb[col] - bn_m[col]) * bs + bn_b[col];
    }
#pragma unroll
    for (int mi = 0; mi < 4; ++mi) {
      const int row0 = m0 + wm + mi * 16 + (lq << 2);
#pragma unroll
      for (int r = 0; r < 4; ++r) {
        if (ok) {
          const float v = fmaxf(acc[mi][ni][r] * bs + bsh, 0.0f);
          Out[(long long)(row0 + r) * CoutReal + col] = f2b(v);
        }
      }
    }
  }
}

// --------------------------- auxiliary kernels -----------------------------

// patches f32 [64][3][128][128] -> A_pe bf16 [4096 tok][768] (k=c*256+ky*16+kx)
__global__ void pe_gather(const float* __restrict__ patches, u16* __restrict__ Ape) {
  const int t = blockIdx.x, tid = threadIdx.x;
  const int img = t >> 6, pos = t & 63, ty = pos >> 3, tx = pos & 7;
  const float* base = patches + (long long)img * 3 * 128 * 128;
  u16* dst = Ape + (long long)t * 768;
  for (int k = tid; k < 768; k += 256) {
    const int c = k >> 8, rr = k & 255, ky = rr >> 4, kx = rr & 15;
    dst[k] = f2b(base[c * 16384 + (ty * 16 + ky) * 128 + tx * 16 + kx]);
  }
}

// V slice of qkv -> Vt [z=bq*8+h][128 d][512 t] bf16 (LDS transpose)
__global__ void vt_transpose(const u16* __restrict__ qkv, u16* __restrict__ Vt) {
  __shared__ u16 lds[64 * 130];
  const int tt = blockIdx.x;       // t-tile 0..7
  const int z = blockIdx.y;        // 0..63
  const int bq = z >> 3, h = z & 7;
  const int tid = threadIdx.x;
  for (int idx = tid; idx < 64 * 128; idx += 256) {
    const int t = idx >> 7, d = idx & 127;
    lds[t * 130 + d] = qkv[(long long)(bq * 512 + tt * 64 + t) * 3072 + 2048 + h * 128 + d];
  }
  __syncthreads();
  for (int idx = tid; idx < 64 * 128; idx += 256) {
    const int d = idx >> 6, t = idx & 63;
    Vt[(long long)z * 65536 + d * 512 + tt * 64 + t] = lds[t * 130 + d];
  }
}

// in-place row softmax with 1/sqrt(128) scale on bf16 rows of 512
__global__ __launch_bounds__(256) void softmax_rows(u16* __restrict__ P) {
  __shared__ float red[8];
  const long long base = (long long)blockIdx.x * 512;
  const int tid = threadIdx.x;
  const float sc = 0.08838834764831845f;
  float x0 = b2f(P[base + tid]) * sc;
  float x1 = b2f(P[base + tid + 256]) * sc;
  float mx = fmaxf(x0, x1);
  for (int o = 32; o; o >>= 1) mx = fmaxf(mx, __shfl_down(mx, o));
  if ((tid & 63) == 0) red[tid >> 6] = mx;
  __syncthreads();
  mx = fmaxf(fmaxf(red[0], red[1]), fmaxf(red[2], red[3]));
  const float e0 = expf(x0 - mx), e1 = expf(x1 - mx);
  float s = e0 + e1;
  for (int o = 32; o; o >>= 1) s += __shfl_down(s, o);
  __syncthreads();
  if ((tid & 63) == 0) red[tid >> 6] = s;
  __syncthreads();
  s = red[0] + red[1] + red[2] + red[3];
  const float inv = 1.0f / s;
  P[base + tid] = f2b(e0 * inv);
  P[base + tid + 256] = f2b(e1 * inv);
}

// hs_b = LN(hs_b + P; g,b).  P bf16.  One block per row of 1024.
__global__ __launch_bounds__(256) void ln_kernel(
    u16* __restrict__ hsb, const u16* __restrict__ P,
    const float* __restrict__ gw, const float* __restrict__ bw)
{
  __shared__ float red[8];
  const int r = blockIdx.x, tid = threadIdx.x;
  float x[4], s = 0.0f, s2 = 0.0f;
#pragma unroll
  for (int i = 0; i < 4; ++i) {
    const int c = tid + i * 256;
    const float v = b2f(hsb[(long long)r * 1024 + c]) + b2f(P[(long long)r * 1024 + c]);
    x[i] = v; s += v; s2 += v * v;
  }
  for (int o = 32; o; o >>= 1) { s += __shfl_down(s, o); s2 += __shfl_down(s2, o); }
  if ((tid & 63) == 0) { red[tid >> 6] = s; red[4 + (tid >> 6)] = s2; }
  __syncthreads();
  s  = red[0] + red[1] + red[2] + red[3];
  s2 = red[4] + red[5] + red[6] + red[7];
  const float mean = s * (1.0f / 1024.0f);
  const float var = s2 * (1.0f / 1024.0f) - mean * mean;
  const float inv = rsqrtf(var + 1e-5f);
#pragma unroll
  for (int i = 0; i < 4; ++i) {
    const int c = tid + i * 256;
    const float y = (x[i] - mean) * inv * gw[c] + bw[c];
    hsb[(long long)r * 1024 + c] = f2b(y);
  }
}

// repack conv weights f32 [Cout][Cin][3][3] -> bf16 [Npad][9*Cin]
__global__ void repack_w(const float* __restrict__ src, u16* __restrict__ dst, int Cout, int l2c) {
  const int co = blockIdx.x, tid = threadIdx.x;
  const int Cin = 1 << l2c, K9 = 9 << l2c;
  for (int j = tid; j < K9; j += 256) {
    const int t = j >> l2c, ci = j & (Cin - 1);
    u16 v = 0;
    if (co < Cout) v = f2b(src[(long long)(co * Cin + ci) * 9 + t]);
    dst[(long long)co * K9 + j] = v;
  }
}

// bilinear x2 (half-pixel), bf16 NHWC -> bf16 NHWC (2H x 2W)
__global__ void ups2x(const u16* __restrict__ in, u16* __restrict__ out,
                      int l2h, int l2w, int l2c, long long total)
{
  const long long idx = (long long)blockIdx.x * 256 + threadIdx.x;
  if (idx >= total) return;
  const int H = 1 << l2h, W = 1 << l2w, C = 1 << l2c;
  const int c = (int)(idx & (C - 1));
  long long t = idx >> l2c;
  const int ox = (int)(t & (2 * W - 1)); t >>= (l2w + 1);
  const int oy = (int)(t & (2 * H - 1)); t >>= (l2h + 1);
  const int img = (int)t;
  const int iy = oy >> 1, ix = ox >> 1;
  int y0, y1, x0, x1; float wy0, wy1, wx0, wx1;
  if (oy & 1) { y0 = iy; y1 = min(iy + 1, H - 1); wy0 = 0.75f; wy1 = 0.25f; }
  else        { y0 = max(iy - 1, 0); y1 = iy;     wy0 = 0.25f; wy1 = 0.75f; }
  if (ox & 1) { x0 = ix; x1 = min(ix + 1, W - 1); wx0 = 0.75f; wx1 = 0.25f; }
  else        { x0 = max(ix - 1, 0); x1 = ix;     wx0 = 0.25f; wx1 = 0.75f; }
  const u16* base = in + (((long long)img) << (l2h + l2w + l2c));
  const float v00 = b2f(base[((((long long)y0 << l2w) + x0) << l2c) + c]);
  const float v01 = b2f(base[((((long long)y0 << l2w) + x1) << l2c) + c]);
  const float v10 = b2f(base[((((long long)y1 << l2w) + x0) << l2c) + c]);
  const float v11 = b2f(base[((((long long)y1 << l2w) + x1) << l2c) + c]);
  out[idx] = f2b(wy0 * (wx0 * v00 + wx1 * v01) + wy1 * (wx0 * v10 + wx1 * v11));
}

// 1x1 conv over 64 channels: C4 bf16 [262144][64] -> Z f32 [262144]
__global__ __launch_bounds__(256) void conv1x1_final(
    const u16* __restrict__ C4, const float* __restrict__ w5,
    const float* __restrict__ b5, float* __restrict__ Z)
{
  const int tid = threadIdx.x;
  const int px = blockIdx.x * 4 + (tid >> 6);
  const int lane = tid & 63;
  float v = b2f(C4[(long long)px * 64 + lane]) * w5[lane];
  for (int o = 32; o; o >>= 1) v += __shfl_down(v, o);
  if (lane == 0) Z[px] = v + b5[0];
}

// bilinear x2: Z f32 [64][64][64] -> out FLOAT32 [64][128][128]
__global__ void ups_final(const float* __restrict__ Z, float* __restrict__ out) {
  const int idx = blockIdx.x * 256 + threadIdx.x;
  const int ox = idx & 127, oy = (idx >> 7) & 127, img = idx >> 14;
  const int iy = oy >> 1, ix = ox >> 1;
  int y0, y1, x0, x1; float wy0, wy1, wx0, wx1;
  if (oy & 1) { y0 = iy; y1 = min(iy + 1, 63); wy0 = 0.75f; wy1 = 0.25f; }
  else        { y0 = max(iy - 1, 0); y1 = iy;  wy0 = 0.25f; wy1 = 0.75f; }
  if (ox & 1) { x0 = ix; x1 = min(ix + 1, 63); wx0 = 0.75f; wx1 = 0.25f; }
  else        { x0 = max(ix - 1, 0); x1 = ix;  wx0 = 0.25f; wx1 = 0.75f; }
  const float* zi = Z + (long long)img * 4096;
  const float v = wy0 * (wx0 * zi[y0 * 64 + x0] + wx1 * zi[y0 * 64 + x1]) +
                  wy1 * (wx0 * zi[y1 * 64 + x0] + wx1 * zi[y1 * 64 + x1]);
  out[idx] = v;
}

// ---------------------------------------------------------------------------
extern "C" void kernel_launch(void* const* d_in, const int* in_sizes, int n_in,
                              void* d_out, int out_size, void* d_ws, size_t ws_size,
                              hipStream_t stream)
{
  (void)in_sizes; (void)n_in; (void)out_size;
  if (ws_size < 110395648u) return;   // diagnostic: zero output => ws too small
  const float* patches = (const float*)d_in[0];
  const float* pe_w = (const float*)d_in[1];
  const float* pe_b = (const float*)d_in[2];
  const float* qkv_w = (const float*)d_in[3];
  const float* qkv_b = (const float*)d_in[4];
  const float* out_w = (const float*)d_in[5];
  const float* out_b = (const float*)d_in[6];
  const float* ln1_g = (const float*)d_in[7];
  const float* ln1_b = (const float*)d_in[8];
  const float* ff1_w = (const float*)d_in[9];
  const float* ff1_b = (const float*)d_in[10];
  const float* ff2_w = (const float*)d_in[11];
  const float* ff2_b = (const float*)d_in[12];
  const float* ln2_g = (const float*)d_in[13];
  const float* ln2_b = (const float*)d_in[14];
  const float* dwv[4] = {(const float*)d_in[15], (const float*)d_in[21], (const float*)d_in[27], (const float*)d_in[33]};
  const float* dbv[4] = {(const float*)d_in[16], (const float*)d_in[22], (const float*)d_in[28], (const float*)d_in[34]};
  const float* gv[4]  = {(const float*)d_in[17], (const float*)d_in[23], (const float*)d_in[29], (const float*)d_in[35]};
  const float* bev[4] = {(const float*)d_in[18], (const float*)d_in[24], (const float*)d_in[30], (const float*)d_in[36]};
  const float* mv[4]  = {(const float*)d_in[19], (const float*)d_in[25], (const float*)d_in[31], (const float*)d_in[37]};
  const float* vv[4]  = {(const float*)d_in[20], (const float*)d_in[26], (const float*)d_in[32], (const float*)d_in[38]};
  const float* dw5 = (const float*)d_in[39];
  const float* db5 = (const float*)d_in[40];
  float* outp = (float*)d_out;     // reference output dtype = float32
  char* ws = (char*)d_ws;

  // ---- workspace layout (peak < 110,395,648 B) ----------------------------
  // transformer phase
  u16* HS_B = (u16*)(ws + 0);              // [4096][1024]
  u16* APE  = (u16*)(ws + 8388608);        // [4096][768] (dead before QKV)
  u16* QKV  = (u16*)(ws + 8388608);        // [4096][3072]   ends 33,554,432
  u16* VT   = (u16*)(ws + 33554432);       // [64][128][512] ends 41,943,040
  u16* SF   = (u16*)(ws + 41943040);       // [64][512][512] ends 75,497,472
  u16* FF1G = (u16*)(ws + 41943040);       // [4096][4096] (over dead SF)
  u16* ATT  = (u16*)(ws + 75497472);       // [4096][1024]   ends 83,886,080
  u16* P_B  = (u16*)(ws + 83886080);       // [4096][1024]   ends 92,274,688
  u16* W1   = (u16*)(ws + 92274688);       // 8.39M slot     ends 100,663,296
  u16* W2   = (u16*)(ws + 100663296);      // 8.39M slot     ends 109,051,904
  float* PART_G  = (float*)(ws + 8388608);  // [2][4096][1024] f32 over dead QKV/VT (proj & FF2, post-PV)
  float* PART_PE = (float*)(ws + 41943040); // [2][4096][1024] f32 over SF region (patch-embed phase only)
  // decoder phase (R3-VERIFIED layout; all transformer buffers except HS_B dead)
  u16* WR1 = (u16*)(ws + 8388608);         // [512][9216]    ends 17,825,792
  u16* WR2 = (u16*)(ws + 17825792);        // [256][4608]    ends 20,185,088
  u16* WR3 = (u16*)(ws + 20185088);        // [128][2304]    ends 20,774,912
  u16* C1  = (u16*)(ws + 20774912);        // [4096][512]    ends 24,969,216
  u16* U1  = (u16*)(ws + 24969216);        // [64][16][16][512] ends 41,746,432
  u16* C2  = (u16*)(ws + 41746432);        // [16384][256]   ends 50,135,040
  u16* U2  = (u16*)(ws + 50135040);        // [64][32][32][256] ends 83,689,472
  u16* C3  = (u16*)(ws + 83689472);        // [65536][128]   ends 100,466,688
  u16* U3  = (u16*)(ws + 8388608);         // [64][64][64][128] = 64MB, ends 75,497,472 (over dead WR1-3/C1/U1/C2 + lower U2)
  u16* C4  = (u16*)(ws + 75497472);        // [262144][64]   ends 109,051,904 (over dead upper-U2/C3/W-slots)
  float* PARTC1 = (float*)(ws + 41746432); // conv1 partials [4][4096][512] f32, ends 75,300,864 (C2/U2 region, unwritten at conv1 time)
  float* PARTC2 = (float*)(ws + 50331648); // conv2 partials [2][16384][256] f32, ends 83,886,080 (disjoint from U1 input & C2 output; C3 written later)
  u16* ZPG = (u16*)(ws + 109051904);       // 4096 B zero page (>= 2*Cin zeros for tap-pointer +ci reads)
  u16* WR4 = (u16*)(ws + 109056000);       // [128][1152]    ends 109,350,912
  float* Z = (float*)(ws + 8388608);       // [262144] f32 over dead U3 start (written after conv4)

  // ---- patch embedding (split-K S=2) --------------------------------------
  pe_gather<<<4096, 256, 0, stream>>>(patches, APE);
  cvt_f2b<<<768, 256, 0, stream>>>(pe_w, W1, 786432);
  gemm_bt<<<dim3(8, 32, 2), 256, 0, stream>>>(
      APE, 768, 0, 0, W1, 768, 0, 0,
      HS_B, 1024, 4194304, 0, nullptr, 0, 1, 12, PART_PE);
  reduce_bias<<<4096, 256, 0, stream>>>(PART_PE, 4194304, 2, pe_b, 1024, HS_B, 4194304LL);

  // ---- transformer --------------------------------------------------------
  for (int l = 0; l < 2; ++l) {
    cvt_f2b<<<3072, 256, 0, stream>>>(qkv_w + (long long)l * 3145728, W1, 3145728);
    gemm_bt<<<dim3(24, 32, 1), 256, 0, stream>>>(
        HS_B, 1024, 0, 0, W1, 1024, 0, 0,
        QKV, 3072, 0, 0, qkv_b + l * 3072, 0, 1, 32, nullptr);
    vt_transpose<<<dim3(8, 64), 256, 0, stream>>>(QKV, VT);
    // S = Q K^T for all 64 (batch,head)
    gemm_bt<<<dim3(4, 4, 64), 256, 0, stream>>>(
        QKV, 3072, 1572864, 128, QKV + 1024, 3072, 1572864, 128,
        SF, 512, 2097152, 262144, nullptr, 0, 8, 4, nullptr);
    softmax_rows<<<32768, 256, 0, stream>>>(SF);
    // O = P V
    gemm_bt<<<dim3(1, 4, 64), 256, 0, stream>>>(
        SF, 512, 2097152, 262144, VT, 512, 524288, 65536,
        ATT, 1024, 524288, 128, nullptr, 0, 8, 16, nullptr);
    // proj (split-K S=2; QKV/VT dead now -> PART_G safe)
    cvt_f2b<<<1024, 256, 0, stream>>>(out_w + (long long)l * 1048576, W2, 1048576);
    gemm_bt<<<dim3(8, 32, 2), 256, 0, stream>>>(
        ATT, 1024, 0, 0, W2, 1024, 0, 0,
        P_B, 1024, 4194304, 0, nullptr, 0, 1, 16, PART_G);
    reduce_bias<<<4096, 256, 0, stream>>>(PART_G, 4194304, 2, out_b + l * 1024, 1024, P_B, 4194304LL);
    ln_kernel<<<4096, 256, 0, stream>>>(HS_B, P_B, ln1_g + l * 1024, ln1_b + l * 1024);
    cvt_f2b<<<4096, 256, 0, stream>>>(ff1_w + (long long)l * 4194304, W1, 4194304);
    cvt_f2b<<<4096, 256, 0, stream>>>(ff2_w + (long long)l * 4194304, W2, 4194304);
    gemm_bt<<<dim3(32, 32, 1), 256, 0, stream>>>(
        HS_B, 1024, 0, 0, W1, 1024, 0, 0,
        FF1G, 4096, 0, 0, ff1_b + l * 4096, 1, 1, 32, nullptr);
    // FF2 (split-K S=2, nk=64)
    gemm_bt<<<dim3(8, 32, 2), 256, 0, stream>>>(
        FF1G, 4096, 0, 0, W2, 4096, 0, 0,
        P_B, 1024, 4194304, 0, nullptr, 0, 1, 64, PART_G);
    reduce_bias<<<4096, 256, 0, stream>>>(PART_G, 4194304, 2, ff2_b + l * 1024, 1024, P_B, 4194304LL);
    ln_kernel<<<4096, 256, 0, stream>>>(HS_B, P_B, ln2_g + l * 1024, ln2_b + l * 1024);
  }

  // ---- CNN decoder --------------------------------------------------------
  hipMemsetAsync((void*)ZPG, 0, 4096, stream);
  repack_w<<<512, 256, 0, stream>>>(dwv[0], WR1, 512, 10);
  repack_w<<<256, 256, 0, stream>>>(dwv[1], WR2, 256, 9);
  repack_w<<<128, 256, 0, stream>>>(dwv[2], WR3, 128, 8);
  repack_w<<<128, 256, 0, stream>>>(dwv[3], WR4, 64, 7);

  // conv1: split-K S=4 (1024 blocks, 4/CU), partial [4][4096][512] f32
  conv_gemm<3, 10, 72><<<dim3(32, 8, 4), 256, 0, stream>>>(
      HS_B, WR1, C1, gv[0], bev[0], mv[0], vv[0], dbv[0], ZPG,
      512, PARTC1, 2097152);
  reduce_bn<<<2048, 256, 0, stream>>>(PARTC1, 2097152, 4,
      gv[0], bev[0], mv[0], vv[0], dbv[0], 512, C1, 2097152LL);
  ups2x<<<32768, 256, 0, stream>>>(C1, U1, 3, 3, 9, 8388608LL);
  // conv2: split-K S=2 (1024 blocks), partial [2][16384][256] f32
  conv_gemm<4, 9, 72><<<dim3(128, 4, 2), 256, 0, stream>>>(
      U1, WR2, C2, gv[1], bev[1], mv[1], vv[1], dbv[1], ZPG,
      256, PARTC2, 4194304);
  reduce_bn<<<4096, 256, 0, stream>>>(PARTC2, 4194304, 2,
      gv[1], bev[1], mv[1], vv[1], dbv[1], 256, C2, 4194304LL);
  ups2x<<<65536, 256, 0, stream>>>(C2, U2, 4, 4, 8, 16777216LL);
  conv_gemm<5, 8, 72><<<dim3(512, 2, 1), 256, 0, stream>>>(
      U2, WR3, C3, gv[2], bev[2], mv[2], vv[2], dbv[2], ZPG,
      128, nullptr, 0);
  ups2x<<<131072, 256, 0, stream>>>(C3, U3, 5, 5, 7, 33554432LL);
  conv_gemm<6, 7, 36><<<dim3(2048, 1, 1), 256, 0, stream>>>(
      U3, WR4, C4, gv[3], bev[3], mv[3], vv[3], dbv[3], ZPG,
      64, nullptr, 0);
  conv1x1_final<<<65536, 256, 0, stream>>>(C4, dw5, db5, Z);
  ups_final<<<4096, 256, 0, stream>>>(Z, outp);
}

// Round 8
// 1298.614 us; speedup vs baseline: 1.0004x; 1.0004x over previous
//
#include <hip/hip_runtime.h>
#include <stdint.h>

// ---------------------------------------------------------------------------
// LocalDino forward on MI355X (gfx950).
// Inputs: float32. OUTPUT: float32 (reference dtype). Internal: bf16 + f32 acc.
// Heavy math via mfma_f32_16x16x32_bf16. gemm_bt and conv_gemm use:
//   - counted-vmcnt software pipeline (BUFS=3 convs 1-3 / gemm; BUFS=2 for
//     conv4: R7 showed conv4 grid-rich (8 blocks/CU) but LDS-capped at 4
//     resident, occupancy 22.6% -> halve LDS for 6 resident blocks)
//   - conflict-free XOR-swizzled LDS (R2 verified conflicts -> 0)
//   - SPLIT-K (R3: latency-bound at 1 block/CU; fix = more blocks/CU)
//   - conv K-iteration ci-chunk-outer/tap-inner (R6: fetch 274->82 MB) with
//     compile-time tap pointers (R7: VALUBusy 44->12%).
// Decoder workspace layout is the R3-verified one; partials in audited
// dead regions. conv grid keeps M on blockIdx.x (XCD A-panel sharing).
// ---------------------------------------------------------------------------

typedef unsigned short u16;
typedef __bf16 bf16x8 __attribute__((ext_vector_type(8)));
typedef short  s16x8  __attribute__((ext_vector_type(8)));
typedef float  f32x4  __attribute__((ext_vector_type(4)));

__device__ __forceinline__ float b2f(u16 x) { return __uint_as_float(((unsigned)x) << 16); }
__device__ __forceinline__ u16 f2b(float f) {
  unsigned u = __float_as_uint(f);
  unsigned r = (u + 0x7fffu + ((u >> 16) & 1u)) >> 16;   // RNE
  return (u16)r;
}
__device__ __forceinline__ void async16(u16* lds, const u16* g) {
  __builtin_amdgcn_global_load_lds((const __attribute__((address_space(1))) void*)g,
                                   (__attribute__((address_space(3))) void*)lds, 16, 0, 0);
}
__device__ __forceinline__ float gelu_f(float x) {
  return 0.5f * x * (1.0f + erff(x * 0.70710678118654752f));  // exact gelu
}

// f32 -> bf16 canonicalization
__global__ __launch_bounds__(256) void cvt_f2b(const float* __restrict__ src,
                                               u16* __restrict__ dst, int n) {
  const int i = (blockIdx.x * 256 + threadIdx.x) * 4;
  if (i + 3 < n) {
    const float4 v = *(const float4*)(src + i);
    dst[i] = f2b(v.x); dst[i + 1] = f2b(v.y); dst[i + 2] = f2b(v.z); dst[i + 3] = f2b(v.w);
  }
}

// ---------------------------------------------------------------------------
// bf16 GEMM: C[m,n] = sum_k A[m,k]*B[n,k] (+bias[n]) (+gelu). Cb bf16 output.
// Batched via blockIdx.z: off = (z/ZH)*s?b + (z%ZH)*s?h.
// SPLIT-K mode: Part != nullptr -> blockIdx.z = k-slice (ZH must be 1).
// ---------------------------------------------------------------------------
__global__ __launch_bounds__(256) void gemm_bt(
    const u16* __restrict__ A, int lda, long long sAb, long long sAh,
    const u16* __restrict__ B, int ldb, long long sBb, long long sBh,
    u16* __restrict__ Cb, int ldc, long long sCb, long long sCh,
    const float* __restrict__ bias, int epi, int ZH, int nk,
    float* __restrict__ Part)
{
  __shared__ u16 As[3][128 * 32];
  __shared__ u16 Bs[3][128 * 32];
  const int tid = threadIdx.x;
  const int zb = blockIdx.z / ZH, zh = blockIdx.z % ZH;
  const u16* Ab = A + zb * sAb + zh * sAh;
  const u16* Bb = B + zb * sBb + zh * sBh;
  const int m0 = blockIdx.y << 7, n0 = blockIdx.x << 7;
  const int wave = tid >> 6, lane = tid & 63;
  const int wm = (wave >> 1) << 6, wn = (wave & 1) << 6;
  const int lr = lane & 15, lq = lane >> 4;
  const int rowb = tid >> 2;
  const int koff = Part ? (zb * (nk << 5)) : 0;   // k-slice element offset
  const int kc_e = (((tid & 3) ^ ((tid >> 3) & 3)) << 3);
  const int kslot = ((lq ^ ((lr >> 1) & 3)) << 3);

  const u16* Arow0 = Ab + (long long)(m0 + rowb)      * lda + kc_e + koff;
  const u16* Arow1 = Ab + (long long)(m0 + rowb + 64) * lda + kc_e + koff;
  const u16* Brow0 = Bb + (long long)(n0 + rowb)      * ldb + kc_e + koff;
  const u16* Brow1 = Bb + (long long)(n0 + rowb + 64) * ldb + kc_e + koff;

  f32x4 acc[4][4] = {};

  auto stage = [&](int kt, int b) {
    const int k0 = kt << 5;
    async16(&As[b][tid * 8],         Arow0 + k0);
    async16(&As[b][(tid + 256) * 8], Arow1 + k0);
    async16(&Bs[b][tid * 8],         Brow0 + k0);
    async16(&Bs[b][(tid + 256) * 8], Brow1 + k0);
  };

  stage(0, 0);
  if (nk > 1) stage(1, 1);
  int cur = 0;
  for (int kt = 0; kt < nk; ++kt) {
    if (kt + 2 < nk) {
      int nb = cur + 2; if (nb >= 3) nb -= 3;
      stage(kt + 2, nb);
      asm volatile("s_waitcnt vmcnt(8)" ::: "memory");
    } else if (kt + 1 < nk) {
      asm volatile("s_waitcnt vmcnt(4)" ::: "memory");
    } else {
      asm volatile("s_waitcnt vmcnt(0)" ::: "memory");
    }
    asm volatile("s_barrier" ::: "memory");   // publish tile kt to all waves

    bf16x8 af[4], bfv[4];
#pragma unroll
    for (int mi = 0; mi < 4; ++mi)
      af[mi] = __builtin_bit_cast(bf16x8, *(const s16x8*)&As[cur][((wm + mi * 16 + lr) << 5) + kslot]);
#pragma unroll
    for (int ni = 0; ni < 4; ++ni)
      bfv[ni] = __builtin_bit_cast(bf16x8, *(const s16x8*)&Bs[cur][((wn + ni * 16 + lr) << 5) + kslot]);
#pragma unroll
    for (int mi = 0; mi < 4; ++mi)
#pragma unroll
      for (int ni = 0; ni < 4; ++ni)
        acc[mi][ni] = __builtin_amdgcn_mfma_f32_16x16x32_bf16(af[mi], bfv[ni], acc[mi][ni], 0, 0, 0);

    asm volatile("s_barrier" ::: "memory");   // protect buffer cur
    ++cur; if (cur == 3) cur = 0;
  }

  if (Part) {
    float* P = Part + (long long)zb * sCb;
#pragma unroll
    for (int ni = 0; ni < 4; ++ni) {
      const int col = n0 + wn + ni * 16 + lr;
#pragma unroll
      for (int mi = 0; mi < 4; ++mi) {
        const int row0 = m0 + wm + mi * 16 + (lq << 2);
#pragma unroll
        for (int r = 0; r < 4; ++r)
          P[(long long)(row0 + r) * ldc + col] = acc[mi][ni][r];
      }
    }
    return;
  }

  const long long Co = zb * sCb + zh * sCh;
#pragma unroll
  for (int ni = 0; ni < 4; ++ni) {
    const int col = n0 + wn + ni * 16 + lr;
    const float badd = bias ? bias[col] : 0.0f;
#pragma unroll
    for (int mi = 0; mi < 4; ++mi) {
      const int row0 = m0 + wm + mi * 16 + (lq << 2);
#pragma unroll
      for (int r = 0; r < 4; ++r) {
        float v = acc[mi][ni][r] + badd;
        if (epi == 1) v = gelu_f(v);
        Cb[Co + (long long)(row0 + r) * ldc + col] = f2b(v);
      }
    }
  }
}

// sum S f32 partial planes + bias -> bf16. N pow2. 4 elems/thread.
__global__ __launch_bounds__(256) void reduce_bias(
    const float* __restrict__ Part, long long sPart, int S,
    const float* __restrict__ bias, int N,
    u16* __restrict__ Out, long long total)
{
  const long long i = ((long long)blockIdx.x * 256 + threadIdx.x) * 4;
  if (i >= total) return;
  f32x4 s = *(const f32x4*)(Part + i);
  for (int p = 1; p < S; ++p) {
    const f32x4 v = *(const f32x4*)(Part + (long long)p * sPart + i);
    s[0] += v[0]; s[1] += v[1]; s[2] += v[2]; s[3] += v[3];
  }
  const int colb = (int)(i & (N - 1));
#pragma unroll
  for (int j = 0; j < 4; ++j)
    Out[i + j] = f2b(s[j] + bias[colb + j]);
}

// sum S f32 partial planes + conv-bias + BN(eval) + ReLU -> bf16 NHWC.
__global__ __launch_bounds__(256) void reduce_bn(
    const float* __restrict__ Part, long long sPart, int S,
    const float* __restrict__ bn_g, const float* __restrict__ bn_b,
    const float* __restrict__ bn_m, const float* __restrict__ bn_v,
    const float* __restrict__ cb, int Cout,
    u16* __restrict__ Out, long long total)
{
  const long long i = ((long long)blockIdx.x * 256 + threadIdx.x) * 4;
  if (i >= total) return;
  f32x4 s = *(const f32x4*)(Part + i);
  for (int p = 1; p < S; ++p) {
    const f32x4 v = *(const f32x4*)(Part + (long long)p * sPart + i);
    s[0] += v[0]; s[1] += v[1]; s[2] += v[2]; s[3] += v[3];
  }
  const int colb = (int)(i & (Cout - 1));
#pragma unroll
  for (int j = 0; j < 4; ++j) {
    const int col = colb + j;
    const float inv = rsqrtf(bn_v[col] + 1e-5f);
    const float bs = bn_g[col] * inv;
    const float bsh = (cb[col] - bn_m[col]) * bs + bn_b[col];
    Out[i + j] = f2b(fmaxf(s[j] * bs + bsh, 0.0f));
  }
}

// ---------------------------------------------------------------------------
// Implicit-GEMM conv3x3 SAME, NHWC bf16 in, fused BN(eval)+ReLU, bf16 out.
// K = 9*Cin as (tap*Cin + ci). Wr: [Npad x K] bf16. Tile 128(M on x) x 64(N).
// template <L2W, L2C, NK, BUFS>: BUFS = LDS ring depth. BUFS=3 -> 36 KB,
// stage-ahead 2, vmcnt(6) (R6/R7-verified schedule). BUFS=2 -> 24 KB,
// stage-ahead 1, vmcnt(3), 6 resident blocks/CU (for grid-rich conv4).
// WAR safety (both): reads of phase t-1 retire (compiler lgkmcnt before the
// consuming MFMAs) before that phase's trailing barrier; stage-issue at
// phase t follows it. Iteration ci-chunk-outer / tap-inner with 18
// precomputed tap pointers; invalid taps -> 4 KB zero page.
// ---------------------------------------------------------------------------
template <int L2W, int L2C, int NK, int BUFS>
__global__ __launch_bounds__(256) void conv_gemm(
    const u16* __restrict__ U, const u16* __restrict__ Wr,
    u16* __restrict__ Out,
    const float* __restrict__ bn_g, const float* __restrict__ bn_b,
    const float* __restrict__ bn_m, const float* __restrict__ bn_v,
    const float* __restrict__ cb,
    const u16* __restrict__ zpg,
    int CoutReal,
    float* __restrict__ Part, long long sPart)
{
  constexpr int L2HW = 2 * L2W;
  constexpr int HH = 1 << L2W;          // H == W for all decoder convs
  constexpr int Kdim = 9 << L2C;
  constexpr int OD = NK / 9;            // ci-chunk iterations per slice
  constexpr int AH = BUFS - 1;          // stage-ahead depth
  __shared__ u16 As[BUFS][128 * 32];    // 8 KB per buffer
  __shared__ u16 Bs[BUFS][64 * 32];     // 4 KB per buffer
  const int tid = threadIdx.x;
  const int m0 = blockIdx.x << 7, n0 = blockIdx.y << 6;   // M on x (XCD share)
  const int slice = blockIdx.z;
  const int gdbase = slice * OD;        // starting global ci-chunk
  const int wave = tid >> 6, lane = tid & 63;
  const int wm = (wave >> 1) << 6, wn = (wave & 1) << 5;
  const int lr = lane & 15, lq = lane >> 4;
  const int rowb = tid >> 2;
  const int kc_e = (((tid & 3) ^ ((tid >> 3) & 3)) << 3);
  const int kslot = ((lq ^ ((lr >> 1) & 3)) << 3);
  const int ciStart = (gdbase << 5) + kc_e;   // element offset, < Cin

  // 18 precomputed tap pointers (ciStart folded in).
  const u16* Pt[2][9];
#pragma unroll
  for (int i = 0; i < 2; ++i) {
    const int mrow = m0 + rowb + (i << 6);
    const int img = mrow >> L2HW;
    const int rem = mrow & ((1 << L2HW) - 1);
    const int y = rem >> L2W, x = rem & (HH - 1);
    const long long ibase = (long long)img << L2HW;
#pragma unroll
    for (int tap = 0; tap < 9; ++tap) {
      const int dy = tap / 3, dx = tap % 3;
      const int yy = y + dy - 1, xx = x + dx - 1;
      Pt[i][tap] = ((unsigned)yy < (unsigned)HH && (unsigned)xx < (unsigned)HH)
          ? U + ((((ibase + (yy << L2W) + xx)) << L2C) + ciStart)
          : zpg + ciStart;
    }
  }
  const u16* Bp = Wr + (long long)(n0 + rowb) * Kdim + kc_e + (gdbase << 5);

  f32x4 acc[4][2] = {};

#define STAGE(TAP, CIE, B)                                                 \
  do {                                                                    \
    async16(&As[(B)][tid * 8],         Pt[0][(TAP)] + (CIE));             \
    async16(&As[(B)][(tid + 256) * 8], Pt[1][(TAP)] + (CIE));             \
    async16(&Bs[(B)][tid * 8],         Bp + (CIE) + ((TAP) << L2C));      \
  } while (0)

#define COMPUTE(B)                                                         \
  do {                                                                    \
    bf16x8 af[4], bfv[2];                                                 \
    _Pragma("unroll") for (int mi = 0; mi < 4; ++mi)                      \
      af[mi] = __builtin_bit_cast(bf16x8,                                 \
        *(const s16x8*)&As[(B)][((wm + mi * 16 + lr) << 5) + kslot]);     \
    _Pragma("unroll") for (int ni = 0; ni < 2; ++ni)                      \
      bfv[ni] = __builtin_bit_cast(bf16x8,                                \
        *(const s16x8*)&Bs[(B)][((wn + ni * 16 + lr) << 5) + kslot]);     \
    _Pragma("unroll") for (int mi = 0; mi < 4; ++mi)                      \
      _Pragma("unroll") for (int ni = 0; ni < 2; ++ni)                    \
        acc[mi][ni] = __builtin_amdgcn_mfma_f32_16x16x32_bf16(            \
            af[mi], bfv[ni], acc[mi][ni], 0, 0, 0);                       \
  } while (0)

#define VMCNT_STEADY()                                                     \
  do {                                                                    \
    if constexpr (AH == 2) asm volatile("s_waitcnt vmcnt(6)" ::: "memory");\
    else                   asm volatile("s_waitcnt vmcnt(3)" ::: "memory");\
  } while (0)

  // Prologue: phases 0..AH-1 (od=0) in flight (3*AH loads/thread).
  STAGE(0, 0, 0);
  if constexpr (AH == 2) STAGE(1, 0, 1);

  int cur = 0;
  int ciOff = 0;
  for (int od = 0; od < OD - 1; ++od, ciOff += 32) {
#pragma unroll
    for (int tap = 0; tap < 9; ++tap) {
      int nb = cur + AH; if (nb >= BUFS) nb -= BUFS;
      // Stage phase+AH (wraps into next ci-chunk). The staged buffer was
      // last read AH phases ago; that phase's trailing barrier ordered its
      // ds_reads before this overwrite.
      if (tap + AH < 9) STAGE(tap + AH, ciOff, nb);
      else              STAGE(tap + AH - 9, ciOff + 32, nb);
      VMCNT_STEADY();
      asm volatile("s_barrier" ::: "memory");   // publish current phase
      COMPUTE(cur);
      asm volatile("s_barrier" ::: "memory");   // protect current buffer
      ++cur; if (cur >= BUFS) cur = 0;
    }
  }
  // Epilogue ci-chunk (od = OD-1): drain the pipeline.
#pragma unroll
  for (int tap = 0; tap < 9; ++tap) {
    if (tap + AH < 9) {
      int nb = cur + AH; if (nb >= BUFS) nb -= BUFS;
      STAGE(tap + AH, ciOff, nb);
      VMCNT_STEADY();
    } else if (tap == 7) {      // reachable only when AH == 2
      asm volatile("s_waitcnt vmcnt(3)" ::: "memory");
    } else {                    // tap == 8
      asm volatile("s_waitcnt vmcnt(0)" ::: "memory");
    }
    asm volatile("s_barrier" ::: "memory");
    COMPUTE(cur);
    asm volatile("s_barrier" ::: "memory");
    ++cur; if (cur >= BUFS) cur = 0;
  }
#undef STAGE
#undef COMPUTE
#undef VMCNT_STEADY

  if (Part) {
    float* P = Part + (long long)slice * sPart;
#pragma unroll
    for (int ni = 0; ni < 2; ++ni) {
      const int col = n0 + wn + ni * 16 + lr;
#pragma unroll
      for (int mi = 0; mi < 4; ++mi) {
        const int row0 = m0 + wm + mi * 16 + (lq << 2);
#pragma unroll
        for (int r = 0; r < 4; ++r)
          P[(long long)(row0 + r) * CoutReal + col] = acc[mi][ni][r];
      }
    }
    return;
  }

#pragma unroll
  for (int ni = 0; ni < 2; ++ni) {
    const int col = n0 + wn + ni * 16 + lr;
    const bool ok = col < CoutReal;
    float bs = 0.0f, bsh = 0.0f;
    if (ok) {
      const float inv = rsqrtf(bn_v[col] + 1e-5f);
      bs = bn_g[col] * inv;
      bsh = (cb[col] - bn_m[col]) * bs + bn_b[col];
    }
#pragma unroll
    for (int mi = 0; mi < 4; ++mi) {
      const int row0 = m0 + wm + mi * 16 + (lq << 2);
#pragma unroll
      for (int r = 0; r < 4; ++r) {
        if (ok) {
          const float v = fmaxf(acc[mi][ni][r] * bs + bsh, 0.0f);
          Out[(long long)(row0 + r) * CoutReal + col] = f2b(v);
        }
      }
    }
  }
}

// --------------------------- auxiliary kernels -----------------------------

// patches f32 [64][3][128][128] -> A_pe bf16 [4096 tok][768] (k=c*256+ky*16+kx)
__global__ void pe_gather(const float* __restrict__ patches, u16* __restrict__ Ape) {
  const int t = blockIdx.x, tid = threadIdx.x;
  const int img = t >> 6, pos = t & 63, ty = pos >> 3, tx = pos & 7;
  const float* base = patches + (long long)img * 3 * 128 * 128;
  u16* dst = Ape + (long long)t * 768;
  for (int k = tid; k < 768; k += 256) {
    const int c = k >> 8, rr = k & 255, ky = rr >> 4, kx = rr & 15;
    dst[k] = f2b(base[c * 16384 + (ty * 16 + ky) * 128 + tx * 16 + kx]);
  }
}

// V slice of qkv -> Vt [z=bq*8+h][128 d][512 t] bf16 (LDS transpose)
__global__ void vt_transpose(const u16* __restrict__ qkv, u16* __restrict__ Vt) {
  __shared__ u16 lds[64 * 130];
  const int tt = blockIdx.x;       // t-tile 0..7
  const int z = blockIdx.y;        // 0..63
  const int bq = z >> 3, h = z & 7;
  const int tid = threadIdx.x;
  for (int idx = tid; idx < 64 * 128; idx += 256) {
    const int t = idx >> 7, d = idx & 127;
    lds[t * 130 + d] = qkv[(long long)(bq * 512 + tt * 64 + t) * 3072 + 2048 + h * 128 + d];
  }
  __syncthreads();
  for (int idx = tid; idx < 64 * 128; idx += 256) {
    const int d = idx >> 6, t = idx & 63;
    Vt[(long long)z * 65536 + d * 512 + tt * 64 + t] = lds[t * 130 + d];
  }
}

// in-place row softmax with 1/sqrt(128) scale on bf16 rows of 512
__global__ __launch_bounds__(256) void softmax_rows(u16* __restrict__ P) {
  __shared__ float red[8];
  const long long base = (long long)blockIdx.x * 512;
  const int tid = threadIdx.x;
  const float sc = 0.08838834764831845f;
  float x0 = b2f(P[base + tid]) * sc;
  float x1 = b2f(P[base + tid + 256]) * sc;
  float mx = fmaxf(x0, x1);
  for (int o = 32; o; o >>= 1) mx = fmaxf(mx, __shfl_down(mx, o));
  if ((tid & 63) == 0) red[tid >> 6] = mx;
  __syncthreads();
  mx = fmaxf(fmaxf(red[0], red[1]), fmaxf(red[2], red[3]));
  const float e0 = expf(x0 - mx), e1 = expf(x1 - mx);
  float s = e0 + e1;
  for (int o = 32; o; o >>= 1) s += __shfl_down(s, o);
  __syncthreads();
  if ((tid & 63) == 0) red[tid >> 6] = s;
  __syncthreads();
  s = red[0] + red[1] + red[2] + red[3];
  const float inv = 1.0f / s;
  P[base + tid] = f2b(e0 * inv);
  P[base + tid + 256] = f2b(e1 * inv);
}

// hs_b = LN(hs_b + P; g,b).  P bf16.  One block per row of 1024.
__global__ __launch_bounds__(256) void ln_kernel(
    u16* __restrict__ hsb, const u16* __restrict__ P,
    const float* __restrict__ gw, const float* __restrict__ bw)
{
  __shared__ float red[8];
  const int r = blockIdx.x, tid = threadIdx.x;
  float x[4], s = 0.0f, s2 = 0.0f;
#pragma unroll
  for (int i = 0; i < 4; ++i) {
    const int c = tid + i * 256;
    const float v = b2f(hsb[(long long)r * 1024 + c]) + b2f(P[(long long)r * 1024 + c]);
    x[i] = v; s += v; s2 += v * v;
  }
  for (int o = 32; o; o >>= 1) { s += __shfl_down(s, o); s2 += __shfl_down(s2, o); }
  if ((tid & 63) == 0) { red[tid >> 6] = s; red[4 + (tid >> 6)] = s2; }
  __syncthreads();
  s  = red[0] + red[1] + red[2] + red[3];
  s2 = red[4] + red[5] + red[6] + red[7];
  const float mean = s * (1.0f / 1024.0f);
  const float var = s2 * (1.0f / 1024.0f) - mean * mean;
  const float inv = rsqrtf(var + 1e-5f);
#pragma unroll
  for (int i = 0; i < 4; ++i) {
    const int c = tid + i * 256;
    const float y = (x[i] - mean) * inv * gw[c] + bw[c];
    hsb[(long long)r * 1024 + c] = f2b(y);
  }
}

// repack conv weights f32 [Cout][Cin][3][3] -> bf16 [Npad][9*Cin]
__global__ void repack_w(const float* __restrict__ src, u16* __restrict__ dst, int Cout, int l2c) {
  const int co = blockIdx.x, tid = threadIdx.x;
  const int Cin = 1 << l2c, K9 = 9 << l2c;
  for (int j = tid; j < K9; j += 256) {
    const int t = j >> l2c, ci = j & (Cin - 1);
    u16 v = 0;
    if (co < Cout) v = f2b(src[(long long)(co * Cin + ci) * 9 + t]);
    dst[(long long)co * K9 + j] = v;
  }
}

// bilinear x2 (half-pixel), bf16 NHWC -> bf16 NHWC (2H x 2W)
__global__ void ups2x(const u16* __restrict__ in, u16* __restrict__ out,
                      int l2h, int l2w, int l2c, long long total)
{
  const long long idx = (long long)blockIdx.x * 256 + threadIdx.x;
  if (idx >= total) return;
  const int H = 1 << l2h, W = 1 << l2w, C = 1 << l2c;
  const int c = (int)(idx & (C - 1));
  long long t = idx >> l2c;
  const int ox = (int)(t & (2 * W - 1)); t >>= (l2w + 1);
  const int oy = (int)(t & (2 * H - 1)); t >>= (l2h + 1);
  const int img = (int)t;
  const int iy = oy >> 1, ix = ox >> 1;
  int y0, y1, x0, x1; float wy0, wy1, wx0, wx1;
  if (oy & 1) { y0 = iy; y1 = min(iy + 1, H - 1); wy0 = 0.75f; wy1 = 0.25f; }
  else        { y0 = max(iy - 1, 0); y1 = iy;     wy0 = 0.25f; wy1 = 0.75f; }
  if (ox & 1) { x0 = ix; x1 = min(ix + 1, W - 1); wx0 = 0.75f; wx1 = 0.25f; }
  else        { x0 = max(ix - 1, 0); x1 = ix;     wx0 = 0.25f; wx1 = 0.75f; }
  const u16* base = in + (((long long)img) << (l2h + l2w + l2c));
  const float v00 = b2f(base[((((long long)y0 << l2w) + x0) << l2c) + c]);
  const float v01 = b2f(base[((((long long)y0 << l2w) + x1) << l2c) + c]);
  const float v10 = b2f(base[((((long long)y1 << l2w) + x0) << l2c) + c]);
  const float v11 = b2f(base[((((long long)y1 << l2w) + x1) << l2c) + c]);
  out[idx] = f2b(wy0 * (wx0 * v00 + wx1 * v01) + wy1 * (wx0 * v10 + wx1 * v11));
}

// 1x1 conv over 64 channels: C4 bf16 [262144][64] -> Z f32 [262144]
__global__ __launch_bounds__(256) void conv1x1_final(
    const u16* __restrict__ C4, const float* __restrict__ w5,
    const float* __restrict__ b5, float* __restrict__ Z)
{
  const int tid = threadIdx.x;
  const int px = blockIdx.x * 4 + (tid >> 6);
  const int lane = tid & 63;
  float v = b2f(C4[(long long)px * 64 + lane]) * w5[lane];
  for (int o = 32; o; o >>= 1) v += __shfl_down(v, o);
  if (lane == 0) Z[px] = v + b5[0];
}

// bilinear x2: Z f32 [64][64][64] -> out FLOAT32 [64][128][128]
__global__ void ups_final(const float* __restrict__ Z, float* __restrict__ out) {
  const int idx = blockIdx.x * 256 + threadIdx.x;
  const int ox = idx & 127, oy = (idx >> 7) & 127, img = idx >> 14;
  const int iy = oy >> 1, ix = ox >> 1;
  int y0, y1, x0, x1; float wy0, wy1, wx0, wx1;
  if (oy & 1) { y0 = iy; y1 = min(iy + 1, 63); wy0 = 0.75f; wy1 = 0.25f; }
  else        { y0 = max(iy - 1, 0); y1 = iy;  wy0 = 0.25f; wy1 = 0.75f; }
  if (ox & 1) { x0 = ix; x1 = min(ix + 1, 63); wx0 = 0.75f; wx1 = 0.25f; }
  else        { x0 = max(ix - 1, 0); x1 = ix;  wx0 = 0.25f; wx1 = 0.75f; }
  const float* zi = Z + (long long)img * 4096;
  const float v = wy0 * (wx0 * zi[y0 * 64 + x0] + wx1 * zi[y0 * 64 + x1]) +
                  wy1 * (wx0 * zi[y1 * 64 + x0] + wx1 * zi[y1 * 64 + x1]);
  out[idx] = v;
}

// ---------------------------------------------------------------------------
extern "C" void kernel_launch(void* const* d_in, const int* in_sizes, int n_in,
                              void* d_out, int out_size, void* d_ws, size_t ws_size,
                              hipStream_t stream)
{
  (void)in_sizes; (void)n_in; (void)out_size;
  if (ws_size < 110395648u) return;   // diagnostic: zero output => ws too small
  const float* patches = (const float*)d_in[0];
  const float* pe_w = (const float*)d_in[1];
  const float* pe_b = (const float*)d_in[2];
  const float* qkv_w = (const float*)d_in[3];
  const float* qkv_b = (const float*)d_in[4];
  const float* out_w = (const float*)d_in[5];
  const float* out_b = (const float*)d_in[6];
  const float* ln1_g = (const float*)d_in[7];
  const float* ln1_b = (const float*)d_in[8];
  const float* ff1_w = (const float*)d_in[9];
  const float* ff1_b = (const float*)d_in[10];
  const float* ff2_w = (const float*)d_in[11];
  const float* ff2_b = (const float*)d_in[12];
  const float* ln2_g = (const float*)d_in[13];
  const float* ln2_b = (const float*)d_in[14];
  const float* dwv[4] = {(const float*)d_in[15], (const float*)d_in[21], (const float*)d_in[27], (const float*)d_in[33]};
  const float* dbv[4] = {(const float*)d_in[16], (const float*)d_in[22], (const float*)d_in[28], (const float*)d_in[34]};
  const float* gv[4]  = {(const float*)d_in[17], (const float*)d_in[23], (const float*)d_in[29], (const float*)d_in[35]};
  const float* bev[4] = {(const float*)d_in[18], (const float*)d_in[24], (const float*)d_in[30], (const float*)d_in[36]};
  const float* mv[4]  = {(const float*)d_in[19], (const float*)d_in[25], (const float*)d_in[31], (const float*)d_in[37]};
  const float* vv[4]  = {(const float*)d_in[20], (const float*)d_in[26], (const float*)d_in[32], (const float*)d_in[38]};
  const float* dw5 = (const float*)d_in[39];
  const float* db5 = (const float*)d_in[40];
  float* outp = (float*)d_out;     // reference output dtype = float32
  char* ws = (char*)d_ws;

  // ---- workspace layout (peak < 110,395,648 B) ----------------------------
  // transformer phase
  u16* HS_B = (u16*)(ws + 0);              // [4096][1024]
  u16* APE  = (u16*)(ws + 8388608);        // [4096][768] (dead before QKV)
  u16* QKV  = (u16*)(ws + 8388608);        // [4096][3072]   ends 33,554,432
  u16* VT   = (u16*)(ws + 33554432);       // [64][128][512] ends 41,943,040
  u16* SF   = (u16*)(ws + 41943040);       // [64][512][512] ends 75,497,472
  u16* FF1G = (u16*)(ws + 41943040);       // [4096][4096] (over dead SF)
  u16* ATT  = (u16*)(ws + 75497472);       // [4096][1024]   ends 83,886,080
  u16* P_B  = (u16*)(ws + 83886080);       // [4096][1024]   ends 92,274,688
  u16* W1   = (u16*)(ws + 92274688);       // 8.39M slot     ends 100,663,296
  u16* W2   = (u16*)(ws + 100663296);      // 8.39M slot     ends 109,051,904
  float* PART_G  = (float*)(ws + 8388608);  // [2][4096][1024] f32 over dead QKV/VT (proj & FF2, post-PV)
  float* PART_PE = (float*)(ws + 41943040); // [2][4096][1024] f32 over SF region (patch-embed phase only)
  // decoder phase (R3-VERIFIED layout; all transformer buffers except HS_B dead)
  u16* WR1 = (u16*)(ws + 8388608);         // [512][9216]    ends 17,825,792
  u16* WR2 = (u16*)(ws + 17825792);        // [256][4608]    ends 20,185,088
  u16* WR3 = (u16*)(ws + 20185088);        // [128][2304]    ends 20,774,912
  u16* C1  = (u16*)(ws + 20774912);        // [4096][512]    ends 24,969,216
  u16* U1  = (u16*)(ws + 24969216);        // [64][16][16][512] ends 41,746,432
  u16* C2  = (u16*)(ws + 41746432);        // [16384][256]   ends 50,135,040
  u16* U2  = (u16*)(ws + 50135040);        // [64][32][32][256] ends 83,689,472
  u16* C3  = (u16*)(ws + 83689472);        // [65536][128]   ends 100,466,688
  u16* U3  = (u16*)(ws + 8388608);         // [64][64][64][128] = 64MB, ends 75,497,472 (over dead WR1-3/C1/U1/C2 + lower U2)
  u16* C4  = (u16*)(ws + 75497472);        // [262144][64]   ends 109,051,904 (over dead upper-U2/C3/W-slots)
  float* PARTC1 = (float*)(ws + 41746432); // conv1 partials [4][4096][512] f32, ends 75,300,864 (C2/U2 region, unwritten at conv1 time)
  float* PARTC2 = (float*)(ws + 50331648); // conv2 partials [2][16384][256] f32, ends 83,886,080 (disjoint from U1 input & C2 output; C3 written later)
  u16* ZPG = (u16*)(ws + 109051904);       // 4096 B zero page (>= 2*Cin zeros for tap-pointer +ci reads)
  u16* WR4 = (u16*)(ws + 109056000);       // [128][1152]    ends 109,350,912
  float* Z = (float*)(ws + 8388608);       // [262144] f32 over dead U3 start (written after conv4)

  // ---- patch embedding (split-K S=2) --------------------------------------
  pe_gather<<<4096, 256, 0, stream>>>(patches, APE);
  cvt_f2b<<<768, 256, 0, stream>>>(pe_w, W1, 786432);
  gemm_bt<<<dim3(8, 32, 2), 256, 0, stream>>>(
      APE, 768, 0, 0, W1, 768, 0, 0,
      HS_B, 1024, 4194304, 0, nullptr, 0, 1, 12, PART_PE);
  reduce_bias<<<4096, 256, 0, stream>>>(PART_PE, 4194304, 2, pe_b, 1024, HS_B, 4194304LL);

  // ---- transformer --------------------------------------------------------
  for (int l = 0; l < 2; ++l) {
    cvt_f2b<<<3072, 256, 0, stream>>>(qkv_w + (long long)l * 3145728, W1, 3145728);
    gemm_bt<<<dim3(24, 32, 1), 256, 0, stream>>>(
        HS_B, 1024, 0, 0, W1, 1024, 0, 0,
        QKV, 3072, 0, 0, qkv_b + l * 3072, 0, 1, 32, nullptr);
    vt_transpose<<<dim3(8, 64), 256, 0, stream>>>(QKV, VT);
    // S = Q K^T for all 64 (batch,head)
    gemm_bt<<<dim3(4, 4, 64), 256, 0, stream>>>(
        QKV, 3072, 1572864, 128, QKV + 1024, 3072, 1572864, 128,
        SF, 512, 2097152, 262144, nullptr, 0, 8, 4, nullptr);
    softmax_rows<<<32768, 256, 0, stream>>>(SF);
    // O = P V
    gemm_bt<<<dim3(1, 4, 64), 256, 0, stream>>>(
        SF, 512, 2097152, 262144, VT, 512, 524288, 65536,
        ATT, 1024, 524288, 128, nullptr, 0, 8, 16, nullptr);
    // proj (split-K S=2; QKV/VT dead now -> PART_G safe)
    cvt_f2b<<<1024, 256, 0, stream>>>(out_w + (long long)l * 1048576, W2, 1048576);
    gemm_bt<<<dim3(8, 32, 2), 256, 0, stream>>>(
        ATT, 1024, 0, 0, W2, 1024, 0, 0,
        P_B, 1024, 4194304, 0, nullptr, 0, 1, 16, PART_G);
    reduce_bias<<<4096, 256, 0, stream>>>(PART_G, 4194304, 2, out_b + l * 1024, 1024, P_B, 4194304LL);
    ln_kernel<<<4096, 256, 0, stream>>>(HS_B, P_B, ln1_g + l * 1024, ln1_b + l * 1024);
    cvt_f2b<<<4096, 256, 0, stream>>>(ff1_w + (long long)l * 4194304, W1, 4194304);
    cvt_f2b<<<4096, 256, 0, stream>>>(ff2_w + (long long)l * 4194304, W2, 4194304);
    gemm_bt<<<dim3(32, 32, 1), 256, 0, stream>>>(
        HS_B, 1024, 0, 0, W1, 1024, 0, 0,
        FF1G, 4096, 0, 0, ff1_b + l * 4096, 1, 1, 32, nullptr);
    // FF2 (split-K S=2, nk=64)
    gemm_bt<<<dim3(8, 32, 2), 256, 0, stream>>>(
        FF1G, 4096, 0, 0, W2, 4096, 0, 0,
        P_B, 1024, 4194304, 0, nullptr, 0, 1, 64, PART_G);
    reduce_bias<<<4096, 256, 0, stream>>>(PART_G, 4194304, 2, ff2_b + l * 1024, 1024, P_B, 4194304LL);
    ln_kernel<<<4096, 256, 0, stream>>>(HS_B, P_B, ln2_g + l * 1024, ln2_b + l * 1024);
  }

  // ---- CNN decoder --------------------------------------------------------
  hipMemsetAsync((void*)ZPG, 0, 4096, stream);
  repack_w<<<512, 256, 0, stream>>>(dwv[0], WR1, 512, 10);
  repack_w<<<256, 256, 0, stream>>>(dwv[1], WR2, 256, 9);
  repack_w<<<128, 256, 0, stream>>>(dwv[2], WR3, 128, 8);
  repack_w<<<128, 256, 0, stream>>>(dwv[3], WR4, 64, 7);

  // conv1: split-K S=4 (1024 blocks, 4/CU), partial [4][4096][512] f32
  conv_gemm<3, 10, 72, 3><<<dim3(32, 8, 4), 256, 0, stream>>>(
      HS_B, WR1, C1, gv[0], bev[0], mv[0], vv[0], dbv[0], ZPG,
      512, PARTC1, 2097152);
  reduce_bn<<<2048, 256, 0, stream>>>(PARTC1, 2097152, 4,
      gv[0], bev[0], mv[0], vv[0], dbv[0], 512, C1, 2097152LL);
  ups2x<<<32768, 256, 0, stream>>>(C1, U1, 3, 3, 9, 8388608LL);
  // conv2: split-K S=2 (1024 blocks), partial [2][16384][256] f32
  conv_gemm<4, 9, 72, 3><<<dim3(128, 4, 2), 256, 0, stream>>>(
      U1, WR2, C2, gv[1], bev[1], mv[1], vv[1], dbv[1], ZPG,
      256, PARTC2, 4194304);
  reduce_bn<<<4096, 256, 0, stream>>>(PARTC2, 4194304, 2,
      gv[1], bev[1], mv[1], vv[1], dbv[1], 256, C2, 4194304LL);
  ups2x<<<65536, 256, 0, stream>>>(C2, U2, 4, 4, 8, 16777216LL);
  conv_gemm<5, 8, 72, 3><<<dim3(512, 2, 1), 256, 0, stream>>>(
      U2, WR3, C3, gv[2], bev[2], mv[2], vv[2], dbv[2], ZPG,
      128, nullptr, 0);
  ups2x<<<131072, 256, 0, stream>>>(C3, U3, 5, 5, 7, 33554432LL);
  // conv4: grid-rich (2048 blocks = 8/CU) -> BUFS=2 (24 KB LDS, 6 resident)
  conv_gemm<6, 7, 36, 2><<<dim3(2048, 1, 1), 256, 0, stream>>>(
      U3, WR4, C4, gv[3], bev[3], mv[3], vv[3], dbv[3], ZPG,
      64, nullptr, 0);
  conv1x1_final<<<65536, 256, 0, stream>>>(C4, dw5, db5, Z);
  ups_final<<<4096, 256, 0, stream>>>(Z, outp);
}

// Round 9
// 1220.849 us; speedup vs baseline: 1.0641x; 1.0637x over previous
//
#include <hip/hip_runtime.h>
#include <stdint.h>

// ---------------------------------------------------------------------------
// LocalDino forward on MI355X (gfx950).
// Inputs: float32. OUTPUT: float32 (reference dtype). Internal: bf16 + f32 acc.
// Heavy math via mfma_f32_16x16x32_bf16. gemm_bt and conv_gemm use:
//   - counted-vmcnt software pipeline (BUFS=3 convs 1-3 / gemm; BUFS=2 conv4)
//   - conflict-free XOR-swizzled LDS (R2 verified conflicts -> 0)
//   - SPLIT-K (R3: latency-bound at 1 block/CU; fix = more blocks/CU)
//   - conv K-iteration ci-chunk-outer/tap-inner (R6: fetch 274->82 MB) with
//     compile-time tap pointers (R7: VALUBusy 44->12%).
// R9: ALL aux kernels vectorized (Guideline 13 — scalar bf16 was ~2x on
// ups2x/ln/softmax/cvt/reduce/pe_gather; ~350 MB of aux traffic).
// Decoder workspace layout is the R3-verified one; partials in audited
// dead regions. conv grid keeps M on blockIdx.x (XCD A-panel sharing).
// ---------------------------------------------------------------------------

typedef unsigned short u16;
typedef __bf16 bf16x8 __attribute__((ext_vector_type(8)));
typedef short  s16x8  __attribute__((ext_vector_type(8)));
typedef float  f32x4  __attribute__((ext_vector_type(4)));
typedef u16    u16x4  __attribute__((ext_vector_type(4)));

__device__ __forceinline__ float b2f(u16 x) { return __uint_as_float(((unsigned)x) << 16); }
__device__ __forceinline__ u16 f2b(float f) {
  unsigned u = __float_as_uint(f);
  unsigned r = (u + 0x7fffu + ((u >> 16) & 1u)) >> 16;   // RNE
  return (u16)r;
}
__device__ __forceinline__ void async16(u16* lds, const u16* g) {
  __builtin_amdgcn_global_load_lds((const __attribute__((address_space(1))) void*)g,
                                   (__attribute__((address_space(3))) void*)lds, 16, 0, 0);
}
__device__ __forceinline__ float gelu_f(float x) {
  return 0.5f * x * (1.0f + erff(x * 0.70710678118654752f));  // exact gelu
}

// f32 -> bf16 canonicalization (vector load + packed store)
__global__ __launch_bounds__(256) void cvt_f2b(const float* __restrict__ src,
                                               u16* __restrict__ dst, int n) {
  const int i = (blockIdx.x * 256 + threadIdx.x) * 4;
  if (i + 3 < n) {
    const float4 v = *(const float4*)(src + i);
    u16x4 o; o.x = f2b(v.x); o.y = f2b(v.y); o.z = f2b(v.z); o.w = f2b(v.w);
    *(u16x4*)(dst + i) = o;
  }
}

// ---------------------------------------------------------------------------
// bf16 GEMM: C[m,n] = sum_k A[m,k]*B[n,k] (+bias[n]) (+gelu). Cb bf16 output.
// Batched via blockIdx.z: off = (z/ZH)*s?b + (z%ZH)*s?h.
// SPLIT-K mode: Part != nullptr -> blockIdx.z = k-slice (ZH must be 1).
// ---------------------------------------------------------------------------
__global__ __launch_bounds__(256) void gemm_bt(
    const u16* __restrict__ A, int lda, long long sAb, long long sAh,
    const u16* __restrict__ B, int ldb, long long sBb, long long sBh,
    u16* __restrict__ Cb, int ldc, long long sCb, long long sCh,
    const float* __restrict__ bias, int epi, int ZH, int nk,
    float* __restrict__ Part)
{
  __shared__ u16 As[3][128 * 32];
  __shared__ u16 Bs[3][128 * 32];
  const int tid = threadIdx.x;
  const int zb = blockIdx.z / ZH, zh = blockIdx.z % ZH;
  const u16* Ab = A + zb * sAb + zh * sAh;
  const u16* Bb = B + zb * sBb + zh * sBh;
  const int m0 = blockIdx.y << 7, n0 = blockIdx.x << 7;
  const int wave = tid >> 6, lane = tid & 63;
  const int wm = (wave >> 1) << 6, wn = (wave & 1) << 6;
  const int lr = lane & 15, lq = lane >> 4;
  const int rowb = tid >> 2;
  const int koff = Part ? (zb * (nk << 5)) : 0;   // k-slice element offset
  const int kc_e = (((tid & 3) ^ ((tid >> 3) & 3)) << 3);
  const int kslot = ((lq ^ ((lr >> 1) & 3)) << 3);

  const u16* Arow0 = Ab + (long long)(m0 + rowb)      * lda + kc_e + koff;
  const u16* Arow1 = Ab + (long long)(m0 + rowb + 64) * lda + kc_e + koff;
  const u16* Brow0 = Bb + (long long)(n0 + rowb)      * ldb + kc_e + koff;
  const u16* Brow1 = Bb + (long long)(n0 + rowb + 64) * ldb + kc_e + koff;

  f32x4 acc[4][4] = {};

  auto stage = [&](int kt, int b) {
    const int k0 = kt << 5;
    async16(&As[b][tid * 8],         Arow0 + k0);
    async16(&As[b][(tid + 256) * 8], Arow1 + k0);
    async16(&Bs[b][tid * 8],         Brow0 + k0);
    async16(&Bs[b][(tid + 256) * 8], Brow1 + k0);
  };

  stage(0, 0);
  if (nk > 1) stage(1, 1);
  int cur = 0;
  for (int kt = 0; kt < nk; ++kt) {
    if (kt + 2 < nk) {
      int nb = cur + 2; if (nb >= 3) nb -= 3;
      stage(kt + 2, nb);
      asm volatile("s_waitcnt vmcnt(8)" ::: "memory");
    } else if (kt + 1 < nk) {
      asm volatile("s_waitcnt vmcnt(4)" ::: "memory");
    } else {
      asm volatile("s_waitcnt vmcnt(0)" ::: "memory");
    }
    asm volatile("s_barrier" ::: "memory");   // publish tile kt to all waves

    bf16x8 af[4], bfv[4];
#pragma unroll
    for (int mi = 0; mi < 4; ++mi)
      af[mi] = __builtin_bit_cast(bf16x8, *(const s16x8*)&As[cur][((wm + mi * 16 + lr) << 5) + kslot]);
#pragma unroll
    for (int ni = 0; ni < 4; ++ni)
      bfv[ni] = __builtin_bit_cast(bf16x8, *(const s16x8*)&Bs[cur][((wn + ni * 16 + lr) << 5) + kslot]);
#pragma unroll
    for (int mi = 0; mi < 4; ++mi)
#pragma unroll
      for (int ni = 0; ni < 4; ++ni)
        acc[mi][ni] = __builtin_amdgcn_mfma_f32_16x16x32_bf16(af[mi], bfv[ni], acc[mi][ni], 0, 0, 0);

    asm volatile("s_barrier" ::: "memory");   // protect buffer cur
    ++cur; if (cur == 3) cur = 0;
  }

  if (Part) {
    float* P = Part + (long long)zb * sCb;
#pragma unroll
    for (int ni = 0; ni < 4; ++ni) {
      const int col = n0 + wn + ni * 16 + lr;
#pragma unroll
      for (int mi = 0; mi < 4; ++mi) {
        const int row0 = m0 + wm + mi * 16 + (lq << 2);
#pragma unroll
        for (int r = 0; r < 4; ++r)
          P[(long long)(row0 + r) * ldc + col] = acc[mi][ni][r];
      }
    }
    return;
  }

  const long long Co = zb * sCb + zh * sCh;
#pragma unroll
  for (int ni = 0; ni < 4; ++ni) {
    const int col = n0 + wn + ni * 16 + lr;
    const float badd = bias ? bias[col] : 0.0f;
#pragma unroll
    for (int mi = 0; mi < 4; ++mi) {
      const int row0 = m0 + wm + mi * 16 + (lq << 2);
#pragma unroll
      for (int r = 0; r < 4; ++r) {
        float v = acc[mi][ni][r] + badd;
        if (epi == 1) v = gelu_f(v);
        Cb[Co + (long long)(row0 + r) * ldc + col] = f2b(v);
      }
    }
  }
}

// sum S f32 partial planes + bias -> bf16 (packed store). N pow2. 4 elems/thread.
__global__ __launch_bounds__(256) void reduce_bias(
    const float* __restrict__ Part, long long sPart, int S,
    const float* __restrict__ bias, int N,
    u16* __restrict__ Out, long long total)
{
  const long long i = ((long long)blockIdx.x * 256 + threadIdx.x) * 4;
  if (i >= total) return;
  f32x4 s = *(const f32x4*)(Part + i);
  for (int p = 1; p < S; ++p) {
    const f32x4 v = *(const f32x4*)(Part + (long long)p * sPart + i);
    s[0] += v[0]; s[1] += v[1]; s[2] += v[2]; s[3] += v[3];
  }
  const int colb = (int)(i & (N - 1));
  u16x4 o;
#pragma unroll
  for (int j = 0; j < 4; ++j)
    o[j] = f2b(s[j] + bias[colb + j]);
  *(u16x4*)(Out + i) = o;
}

// sum S f32 partial planes + conv-bias + BN(eval) + ReLU -> bf16 NHWC (packed).
__global__ __launch_bounds__(256) void reduce_bn(
    const float* __restrict__ Part, long long sPart, int S,
    const float* __restrict__ bn_g, const float* __restrict__ bn_b,
    const float* __restrict__ bn_m, const float* __restrict__ bn_v,
    const float* __restrict__ cb, int Cout,
    u16* __restrict__ Out, long long total)
{
  const long long i = ((long long)blockIdx.x * 256 + threadIdx.x) * 4;
  if (i >= total) return;
  f32x4 s = *(const f32x4*)(Part + i);
  for (int p = 1; p < S; ++p) {
    const f32x4 v = *(const f32x4*)(Part + (long long)p * sPart + i);
    s[0] += v[0]; s[1] += v[1]; s[2] += v[2]; s[3] += v[3];
  }
  const int colb = (int)(i & (Cout - 1));
  u16x4 o;
#pragma unroll
  for (int j = 0; j < 4; ++j) {
    const int col = colb + j;
    const float inv = rsqrtf(bn_v[col] + 1e-5f);
    const float bs = bn_g[col] * inv;
    const float bsh = (cb[col] - bn_m[col]) * bs + bn_b[col];
    o[j] = f2b(fmaxf(s[j] * bs + bsh, 0.0f));
  }
  *(u16x4*)(Out + i) = o;
}

// ---------------------------------------------------------------------------
// Implicit-GEMM conv3x3 SAME, NHWC bf16 in, fused BN(eval)+ReLU, bf16 out.
// template <L2W, L2C, NK, BUFS>: BUFS = LDS ring depth (3 -> 36 KB, vmcnt(6);
// 2 -> 24 KB, vmcnt(3)). Iteration ci-chunk-outer / tap-inner with 18
// precomputed tap pointers; invalid taps -> 4 KB zero page.
// ---------------------------------------------------------------------------
template <int L2W, int L2C, int NK, int BUFS>
__global__ __launch_bounds__(256) void conv_gemm(
    const u16* __restrict__ U, const u16* __restrict__ Wr,
    u16* __restrict__ Out,
    const float* __restrict__ bn_g, const float* __restrict__ bn_b,
    const float* __restrict__ bn_m, const float* __restrict__ bn_v,
    const float* __restrict__ cb,
    const u16* __restrict__ zpg,
    int CoutReal,
    float* __restrict__ Part, long long sPart)
{
  constexpr int L2HW = 2 * L2W;
  constexpr int HH = 1 << L2W;          // H == W for all decoder convs
  constexpr int Kdim = 9 << L2C;
  constexpr int OD = NK / 9;            // ci-chunk iterations per slice
  constexpr int AH = BUFS - 1;          // stage-ahead depth
  __shared__ u16 As[BUFS][128 * 32];    // 8 KB per buffer
  __shared__ u16 Bs[BUFS][64 * 32];     // 4 KB per buffer
  const int tid = threadIdx.x;
  const int m0 = blockIdx.x << 7, n0 = blockIdx.y << 6;   // M on x (XCD share)
  const int slice = blockIdx.z;
  const int gdbase = slice * OD;        // starting global ci-chunk
  const int wave = tid >> 6, lane = tid & 63;
  const int wm = (wave >> 1) << 6, wn = (wave & 1) << 5;
  const int lr = lane & 15, lq = lane >> 4;
  const int rowb = tid >> 2;
  const int kc_e = (((tid & 3) ^ ((tid >> 3) & 3)) << 3);
  const int kslot = ((lq ^ ((lr >> 1) & 3)) << 3);
  const int ciStart = (gdbase << 5) + kc_e;   // element offset, < Cin

  // 18 precomputed tap pointers (ciStart folded in).
  const u16* Pt[2][9];
#pragma unroll
  for (int i = 0; i < 2; ++i) {
    const int mrow = m0 + rowb + (i << 6);
    const int img = mrow >> L2HW;
    const int rem = mrow & ((1 << L2HW) - 1);
    const int y = rem >> L2W, x = rem & (HH - 1);
    const long long ibase = (long long)img << L2HW;
#pragma unroll
    for (int tap = 0; tap < 9; ++tap) {
      const int dy = tap / 3, dx = tap % 3;
      const int yy = y + dy - 1, xx = x + dx - 1;
      Pt[i][tap] = ((unsigned)yy < (unsigned)HH && (unsigned)xx < (unsigned)HH)
          ? U + ((((ibase + (yy << L2W) + xx)) << L2C) + ciStart)
          : zpg + ciStart;
    }
  }
  const u16* Bp = Wr + (long long)(n0 + rowb) * Kdim + kc_e + (gdbase << 5);

  f32x4 acc[4][2] = {};

#define STAGE(TAP, CIE, B)                                                 \
  do {                                                                    \
    async16(&As[(B)][tid * 8],         Pt[0][(TAP)] + (CIE));             \
    async16(&As[(B)][(tid + 256) * 8], Pt[1][(TAP)] + (CIE));             \
    async16(&Bs[(B)][tid * 8],         Bp + (CIE) + ((TAP) << L2C));      \
  } while (0)

#define COMPUTE(B)                                                         \
  do {                                                                    \
    bf16x8 af[4], bfv[2];                                                 \
    _Pragma("unroll") for (int mi = 0; mi < 4; ++mi)                      \
      af[mi] = __builtin_bit_cast(bf16x8,                                 \
        *(const s16x8*)&As[(B)][((wm + mi * 16 + lr) << 5) + kslot]);     \
    _Pragma("unroll") for (int ni = 0; ni < 2; ++ni)                      \
      bfv[ni] = __builtin_bit_cast(bf16x8,                                \
        *(const s16x8*)&Bs[(B)][((wn + ni * 16 + lr) << 5) + kslot]);     \
    _Pragma("unroll") for (int mi = 0; mi < 4; ++mi)                      \
      _Pragma("unroll") for (int ni = 0; ni < 2; ++ni)                    \
        acc[mi][ni] = __builtin_amdgcn_mfma_f32_16x16x32_bf16(            \
            af[mi], bfv[ni], acc[mi][ni], 0, 0, 0);                       \
  } while (0)

#define VMCNT_STEADY()                                                     \
  do {                                                                    \
    if constexpr (AH == 2) asm volatile("s_waitcnt vmcnt(6)" ::: "memory");\
    else                   asm volatile("s_waitcnt vmcnt(3)" ::: "memory");\
  } while (0)

  // Prologue: phases 0..AH-1 (od=0) in flight (3*AH loads/thread).
  STAGE(0, 0, 0);
  if constexpr (AH == 2) STAGE(1, 0, 1);

  int cur = 0;
  int ciOff = 0;
  for (int od = 0; od < OD - 1; ++od, ciOff += 32) {
#pragma unroll
    for (int tap = 0; tap < 9; ++tap) {
      int nb = cur + AH; if (nb >= BUFS) nb -= BUFS;
      // Stage phase+AH (wraps into next ci-chunk). The staged buffer was
      // last read AH phases ago; that phase's trailing barrier ordered its
      // ds_reads before this overwrite.
      if (tap + AH < 9) STAGE(tap + AH, ciOff, nb);
      else              STAGE(tap + AH - 9, ciOff + 32, nb);
      VMCNT_STEADY();
      asm volatile("s_barrier" ::: "memory");   // publish current phase
      COMPUTE(cur);
      asm volatile("s_barrier" ::: "memory");   // protect current buffer
      ++cur; if (cur >= BUFS) cur = 0;
    }
  }
  // Epilogue ci-chunk (od = OD-1): drain the pipeline.
#pragma unroll
  for (int tap = 0; tap < 9; ++tap) {
    if (tap + AH < 9) {
      int nb = cur + AH; if (nb >= BUFS) nb -= BUFS;
      STAGE(tap + AH, ciOff, nb);
      VMCNT_STEADY();
    } else if (tap == 7) {      // reachable only when AH == 2
      asm volatile("s_waitcnt vmcnt(3)" ::: "memory");
    } else {                    // tap == 8
      asm volatile("s_waitcnt vmcnt(0)" ::: "memory");
    }
    asm volatile("s_barrier" ::: "memory");
    COMPUTE(cur);
    asm volatile("s_barrier" ::: "memory");
    ++cur; if (cur >= BUFS) cur = 0;
  }
#undef STAGE
#undef COMPUTE
#undef VMCNT_STEADY

  if (Part) {
    float* P = Part + (long long)slice * sPart;
#pragma unroll
    for (int ni = 0; ni < 2; ++ni) {
      const int col = n0 + wn + ni * 16 + lr;
#pragma unroll
      for (int mi = 0; mi < 4; ++mi) {
        const int row0 = m0 + wm + mi * 16 + (lq << 2);
#pragma unroll
        for (int r = 0; r < 4; ++r)
          P[(long long)(row0 + r) * CoutReal + col] = acc[mi][ni][r];
      }
    }
    return;
  }

#pragma unroll
  for (int ni = 0; ni < 2; ++ni) {
    const int col = n0 + wn + ni * 16 + lr;
    const bool ok = col < CoutReal;
    float bs = 0.0f, bsh = 0.0f;
    if (ok) {
      const float inv = rsqrtf(bn_v[col] + 1e-5f);
      bs = bn_g[col] * inv;
      bsh = (cb[col] - bn_m[col]) * bs + bn_b[col];
    }
#pragma unroll
    for (int mi = 0; mi < 4; ++mi) {
      const int row0 = m0 + wm + mi * 16 + (lq << 2);
#pragma unroll
      for (int r = 0; r < 4; ++r) {
        if (ok) {
          const float v = fmaxf(acc[mi][ni][r] * bs + bsh, 0.0f);
          Out[(long long)(row0 + r) * CoutReal + col] = f2b(v);
        }
      }
    }
  }
}

// --------------------------- auxiliary kernels -----------------------------

// patches f32 [64][3][128][128] -> A_pe bf16 [4096 tok][768] (k=c*256+ky*16+kx)
// vectorized: float4 load -> ushort4 store (kx groups of 4 are contiguous).
__global__ void pe_gather(const float* __restrict__ patches, u16* __restrict__ Ape) {
  const int t = blockIdx.x, tid = threadIdx.x;
  const int img = t >> 6, pos = t & 63, ty = pos >> 3, tx = pos & 7;
  const float* base = patches + (long long)img * 3 * 128 * 128;
  u16* dst = Ape + (long long)t * 768;
  const int k = tid << 2;
  if (k < 768) {
    const int c = k >> 8, rr = k & 255, ky = rr >> 4, kx = rr & 15;
    const float4 v = *(const float4*)&base[c * 16384 + (ty * 16 + ky) * 128 + tx * 16 + kx];
    u16x4 o; o.x = f2b(v.x); o.y = f2b(v.y); o.z = f2b(v.z); o.w = f2b(v.w);
    *(u16x4*)&dst[k] = o;
  }
}

// V slice of qkv -> Vt [z=bq*8+h][128 d][512 t] bf16 (LDS transpose)
__global__ void vt_transpose(const u16* __restrict__ qkv, u16* __restrict__ Vt) {
  __shared__ u16 lds[64 * 130];
  const int tt = blockIdx.x;       // t-tile 0..7
  const int z = blockIdx.y;        // 0..63
  const int bq = z >> 3, h = z & 7;
  const int tid = threadIdx.x;
  for (int idx = tid; idx < 64 * 128; idx += 256) {
    const int t = idx >> 7, d = idx & 127;
    lds[t * 130 + d] = qkv[(long long)(bq * 512 + tt * 64 + t) * 3072 + 2048 + h * 128 + d];
  }
  __syncthreads();
  for (int idx = tid; idx < 64 * 128; idx += 256) {
    const int d = idx >> 6, t = idx & 63;
    Vt[(long long)z * 65536 + d * 512 + tt * 64 + t] = lds[t * 130 + d];
  }
}

// in-place row softmax with 1/sqrt(128) scale on bf16 rows of 512.
// vectorized: each thread owns 2 consecutive elems as one u32.
__global__ __launch_bounds__(256) void softmax_rows(u16* __restrict__ P) {
  __shared__ float red[8];
  const long long base = (long long)blockIdx.x * 512;
  const int tid = threadIdx.x;
  const float sc = 0.08838834764831845f;
  const unsigned vv = *(const unsigned*)&P[base + (tid << 1)];
  float x0 = b2f((u16)(vv & 0xffffu)) * sc;
  float x1 = b2f((u16)(vv >> 16)) * sc;
  float mx = fmaxf(x0, x1);
  for (int o = 32; o; o >>= 1) mx = fmaxf(mx, __shfl_down(mx, o));
  if ((tid & 63) == 0) red[tid >> 6] = mx;
  __syncthreads();
  mx = fmaxf(fmaxf(red[0], red[1]), fmaxf(red[2], red[3]));
  const float e0 = expf(x0 - mx), e1 = expf(x1 - mx);
  float s = e0 + e1;
  for (int o = 32; o; o >>= 1) s += __shfl_down(s, o);
  __syncthreads();
  if ((tid & 63) == 0) red[tid >> 6] = s;
  __syncthreads();
  s = red[0] + red[1] + red[2] + red[3];
  const float inv = 1.0f / s;
  const unsigned oo = (unsigned)f2b(e0 * inv) | ((unsigned)f2b(e1 * inv) << 16);
  *(unsigned*)&P[base + (tid << 1)] = oo;
}

// hs_b = LN(hs_b + P; g,b).  P bf16.  One block per row of 1024.
// vectorized: each thread owns 4 consecutive cols (ushort4 loads/stores).
__global__ __launch_bounds__(256) void ln_kernel(
    u16* __restrict__ hsb, const u16* __restrict__ P,
    const float* __restrict__ gw, const float* __restrict__ bw)
{
  __shared__ float red[8];
  const int r = blockIdx.x, tid = threadIdx.x;
  const int c0 = tid << 2;
  const u16x4 hv = *(const u16x4*)&hsb[(long long)r * 1024 + c0];
  const u16x4 pv = *(const u16x4*)&P[(long long)r * 1024 + c0];
  float x[4], s = 0.0f, s2 = 0.0f;
#pragma unroll
  for (int i = 0; i < 4; ++i) {
    const float v = b2f(hv[i]) + b2f(pv[i]);
    x[i] = v; s += v; s2 += v * v;
  }
  for (int o = 32; o; o >>= 1) { s += __shfl_down(s, o); s2 += __shfl_down(s2, o); }
  if ((tid & 63) == 0) { red[tid >> 6] = s; red[4 + (tid >> 6)] = s2; }
  __syncthreads();
  s  = red[0] + red[1] + red[2] + red[3];
  s2 = red[4] + red[5] + red[6] + red[7];
  const float mean = s * (1.0f / 1024.0f);
  const float var = s2 * (1.0f / 1024.0f) - mean * mean;
  const float inv = rsqrtf(var + 1e-5f);
  u16x4 o;
#pragma unroll
  for (int i = 0; i < 4; ++i) {
    const float y = (x[i] - mean) * inv * gw[c0 + i] + bw[c0 + i];
    o[i] = f2b(y);
  }
  *(u16x4*)&hsb[(long long)r * 1024 + c0] = o;
}

// repack conv weights f32 [Cout][Cin][3][3] -> bf16 [Npad][9*Cin]
__global__ void repack_w(const float* __restrict__ src, u16* __restrict__ dst, int Cout, int l2c) {
  const int co = blockIdx.x, tid = threadIdx.x;
  const int Cin = 1 << l2c, K9 = 9 << l2c;
  for (int j = tid; j < K9; j += 256) {
    const int t = j >> l2c, ci = j & (Cin - 1);
    u16 v = 0;
    if (co < Cout) v = f2b(src[(long long)(co * Cin + ci) * 9 + t]);
    dst[(long long)co * K9 + j] = v;
  }
}

// bilinear x2 (half-pixel), bf16 NHWC -> bf16 NHWC (2H x 2W).
// vectorized: each thread processes 8 consecutive channels (short8).
// totalg = output elements / 8.
__global__ void ups2x(const u16* __restrict__ in, u16* __restrict__ out,
                      int l2h, int l2w, int l2c, long long totalg)
{
  const long long idx = (long long)blockIdx.x * 256 + threadIdx.x;
  if (idx >= totalg) return;
  const int H = 1 << l2h, W = 1 << l2w;
  const int cg = (int)(idx & ((1 << (l2c - 3)) - 1));
  long long t = idx >> (l2c - 3);
  const int ox = (int)(t & (2 * W - 1)); t >>= (l2w + 1);
  const int oy = (int)(t & (2 * H - 1)); t >>= (l2h + 1);
  const int img = (int)t;
  const int iy = oy >> 1, ix = ox >> 1;
  int y0, y1, x0, x1; float wy0, wy1, wx0, wx1;
  if (oy & 1) { y0 = iy; y1 = min(iy + 1, H - 1); wy0 = 0.75f; wy1 = 0.25f; }
  else        { y0 = max(iy - 1, 0); y1 = iy;     wy0 = 0.25f; wy1 = 0.75f; }
  if (ox & 1) { x0 = ix; x1 = min(ix + 1, W - 1); wx0 = 0.75f; wx1 = 0.25f; }
  else        { x0 = max(ix - 1, 0); x1 = ix;     wx0 = 0.25f; wx1 = 0.75f; }
  const u16* base = in + (((long long)img) << (l2h + l2w + l2c));
  const int c0 = cg << 3;
  const s16x8 v00 = *(const s16x8*)&base[((((long long)y0 << l2w) + x0) << l2c) + c0];
  const s16x8 v01 = *(const s16x8*)&base[((((long long)y0 << l2w) + x1) << l2c) + c0];
  const s16x8 v10 = *(const s16x8*)&base[((((long long)y1 << l2w) + x0) << l2c) + c0];
  const s16x8 v11 = *(const s16x8*)&base[((((long long)y1 << l2w) + x1) << l2c) + c0];
  s16x8 o;
#pragma unroll
  for (int j = 0; j < 8; ++j) {
    const float v = wy0 * (wx0 * b2f((u16)v00[j]) + wx1 * b2f((u16)v01[j])) +
                    wy1 * (wx0 * b2f((u16)v10[j]) + wx1 * b2f((u16)v11[j]));
    o[j] = (short)f2b(v);
  }
  *(s16x8*)&out[idx << 3] = o;
}

// 1x1 conv over 64 channels: C4 bf16 [262144][64] -> Z f32 [262144]
__global__ __launch_bounds__(256) void conv1x1_final(
    const u16* __restrict__ C4, const float* __restrict__ w5,
    const float* __restrict__ b5, float* __restrict__ Z)
{
  const int tid = threadIdx.x;
  const int px = blockIdx.x * 4 + (tid >> 6);
  const int lane = tid & 63;
  float v = b2f(C4[(long long)px * 64 + lane]) * w5[lane];
  for (int o = 32; o; o >>= 1) v += __shfl_down(v, o);
  if (lane == 0) Z[px] = v + b5[0];
}

// bilinear x2: Z f32 [64][64][64] -> out FLOAT32 [64][128][128]
__global__ void ups_final(const float* __restrict__ Z, float* __restrict__ out) {
  const int idx = blockIdx.x * 256 + threadIdx.x;
  const int ox = idx & 127, oy = (idx >> 7) & 127, img = idx >> 14;
  const int iy = oy >> 1, ix = ox >> 1;
  int y0, y1, x0, x1; float wy0, wy1, wx0, wx1;
  if (oy & 1) { y0 = iy; y1 = min(iy + 1, 63); wy0 = 0.75f; wy1 = 0.25f; }
  else        { y0 = max(iy - 1, 0); y1 = iy;  wy0 = 0.25f; wy1 = 0.75f; }
  if (ox & 1) { x0 = ix; x1 = min(ix + 1, 63); wx0 = 0.75f; wx1 = 0.25f; }
  else        { x0 = max(ix - 1, 0); x1 = ix;  wx0 = 0.25f; wx1 = 0.75f; }
  const float* zi = Z + (long long)img * 4096;
  const float v = wy0 * (wx0 * zi[y0 * 64 + x0] + wx1 * zi[y0 * 64 + x1]) +
                  wy1 * (wx0 * zi[y1 * 64 + x0] + wx1 * zi[y1 * 64 + x1]);
  out[idx] = v;
}

// ---------------------------------------------------------------------------
extern "C" void kernel_launch(void* const* d_in, const int* in_sizes, int n_in,
                              void* d_out, int out_size, void* d_ws, size_t ws_size,
                              hipStream_t stream)
{
  (void)in_sizes; (void)n_in; (void)out_size;
  if (ws_size < 110395648u) return;   // diagnostic: zero output => ws too small
  const float* patches = (const float*)d_in[0];
  const float* pe_w = (const float*)d_in[1];
  const float* pe_b = (const float*)d_in[2];
  const float* qkv_w = (const float*)d_in[3];
  const float* qkv_b = (const float*)d_in[4];
  const float* out_w = (const float*)d_in[5];
  const float* out_b = (const float*)d_in[6];
  const float* ln1_g = (const float*)d_in[7];
  const float* ln1_b = (const float*)d_in[8];
  const float* ff1_w = (const float*)d_in[9];
  const float* ff1_b = (const float*)d_in[10];
  const float* ff2_w = (const float*)d_in[11];
  const float* ff2_b = (const float*)d_in[12];
  const float* ln2_g = (const float*)d_in[13];
  const float* ln2_b = (const float*)d_in[14];
  const float* dwv[4] = {(const float*)d_in[15], (const float*)d_in[21], (const float*)d_in[27], (const float*)d_in[33]};
  const float* dbv[4] = {(const float*)d_in[16], (const float*)d_in[22], (const float*)d_in[28], (const float*)d_in[34]};
  const float* gv[4]  = {(const float*)d_in[17], (const float*)d_in[23], (const float*)d_in[29], (const float*)d_in[35]};
  const float* bev[4] = {(const float*)d_in[18], (const float*)d_in[24], (const float*)d_in[30], (const float*)d_in[36]};
  const float* mv[4]  = {(const float*)d_in[19], (const float*)d_in[25], (const float*)d_in[31], (const float*)d_in[37]};
  const float* vv[4]  = {(const float*)d_in[20], (const float*)d_in[26], (const float*)d_in[32], (const float*)d_in[38]};
  const float* dw5 = (const float*)d_in[39];
  const float* db5 = (const float*)d_in[40];
  float* outp = (float*)d_out;     // reference output dtype = float32
  char* ws = (char*)d_ws;

  // ---- workspace layout (peak < 110,395,648 B) ----------------------------
  // transformer phase
  u16* HS_B = (u16*)(ws + 0);              // [4096][1024]
  u16* APE  = (u16*)(ws + 8388608);        // [4096][768] (dead before QKV)
  u16* QKV  = (u16*)(ws + 8388608);        // [4096][3072]   ends 33,554,432
  u16* VT   = (u16*)(ws + 33554432);       // [64][128][512] ends 41,943,040
  u16* SF   = (u16*)(ws + 41943040);       // [64][512][512] ends 75,497,472
  u16* FF1G = (u16*)(ws + 41943040);       // [4096][4096] (over dead SF)
  u16* ATT  = (u16*)(ws + 75497472);       // [4096][1024]   ends 83,886,080
  u16* P_B  = (u16*)(ws + 83886080);       // [4096][1024]   ends 92,274,688
  u16* W1   = (u16*)(ws + 92274688);       // 8.39M slot     ends 100,663,296
  u16* W2   = (u16*)(ws + 100663296);      // 8.39M slot     ends 109,051,904
  float* PART_G  = (float*)(ws + 8388608);  // [2][4096][1024] f32 over dead QKV/VT (proj & FF2, post-PV)
  float* PART_PE = (float*)(ws + 41943040); // [2][4096][1024] f32 over SF region (patch-embed phase only)
  // decoder phase (R3-VERIFIED layout; all transformer buffers except HS_B dead)
  u16* WR1 = (u16*)(ws + 8388608);         // [512][9216]    ends 17,825,792
  u16* WR2 = (u16*)(ws + 17825792);        // [256][4608]    ends 20,185,088
  u16* WR3 = (u16*)(ws + 20185088);        // [128][2304]    ends 20,774,912
  u16* C1  = (u16*)(ws + 20774912);        // [4096][512]    ends 24,969,216
  u16* U1  = (u16*)(ws + 24969216);        // [64][16][16][512] ends 41,746,432
  u16* C2  = (u16*)(ws + 41746432);        // [16384][256]   ends 50,135,040
  u16* U2  = (u16*)(ws + 50135040);        // [64][32][32][256] ends 83,689,472
  u16* C3  = (u16*)(ws + 83689472);        // [65536][128]   ends 100,466,688
  u16* U3  = (u16*)(ws + 8388608);         // [64][64][64][128] = 64MB, ends 75,497,472 (over dead WR1-3/C1/U1/C2 + lower U2)
  u16* C4  = (u16*)(ws + 75497472);        // [262144][64]   ends 109,051,904 (over dead upper-U2/C3/W-slots)
  float* PARTC1 = (float*)(ws + 41746432); // conv1 partials [4][4096][512] f32, ends 75,300,864 (C2/U2 region, unwritten at conv1 time)
  float* PARTC2 = (float*)(ws + 50331648); // conv2 partials [2][16384][256] f32, ends 83,886,080 (disjoint from U1 input & C2 output; C3 written later)
  u16* ZPG = (u16*)(ws + 109051904);       // 4096 B zero page (>= 2*Cin zeros for tap-pointer +ci reads)
  u16* WR4 = (u16*)(ws + 109056000);       // [128][1152]    ends 109,350,912
  float* Z = (float*)(ws + 8388608);       // [262144] f32 over dead U3 start (written after conv4)

  // ---- patch embedding (split-K S=2) --------------------------------------
  pe_gather<<<4096, 256, 0, stream>>>(patches, APE);
  cvt_f2b<<<768, 256, 0, stream>>>(pe_w, W1, 786432);
  gemm_bt<<<dim3(8, 32, 2), 256, 0, stream>>>(
      APE, 768, 0, 0, W1, 768, 0, 0,
      HS_B, 1024, 4194304, 0, nullptr, 0, 1, 12, PART_PE);
  reduce_bias<<<4096, 256, 0, stream>>>(PART_PE, 4194304, 2, pe_b, 1024, HS_B, 4194304LL);

  // ---- transformer --------------------------------------------------------
  for (int l = 0; l < 2; ++l) {
    cvt_f2b<<<3072, 256, 0, stream>>>(qkv_w + (long long)l * 3145728, W1, 3145728);
    gemm_bt<<<dim3(24, 32, 1), 256, 0, stream>>>(
        HS_B, 1024, 0, 0, W1, 1024, 0, 0,
        QKV, 3072, 0, 0, qkv_b + l * 3072, 0, 1, 32, nullptr);
    vt_transpose<<<dim3(8, 64), 256, 0, stream>>>(QKV, VT);
    // S = Q K^T for all 64 (batch,head)
    gemm_bt<<<dim3(4, 4, 64), 256, 0, stream>>>(
        QKV, 3072, 1572864, 128, QKV + 1024, 3072, 1572864, 128,
        SF, 512, 2097152, 262144, nullptr, 0, 8, 4, nullptr);
    softmax_rows<<<32768, 256, 0, stream>>>(SF);
    // O = P V
    gemm_bt<<<dim3(1, 4, 64), 256, 0, stream>>>(
        SF, 512, 2097152, 262144, VT, 512, 524288, 65536,
        ATT, 1024, 524288, 128, nullptr, 0, 8, 16, nullptr);
    // proj (split-K S=2; QKV/VT dead now -> PART_G safe)
    cvt_f2b<<<1024, 256, 0, stream>>>(out_w + (long long)l * 1048576, W2, 1048576);
    gemm_bt<<<dim3(8, 32, 2), 256, 0, stream>>>(
        ATT, 1024, 0, 0, W2, 1024, 0, 0,
        P_B, 1024, 4194304, 0, nullptr, 0, 1, 16, PART_G);
    reduce_bias<<<4096, 256, 0, stream>>>(PART_G, 4194304, 2, out_b + l * 1024, 1024, P_B, 4194304LL);
    ln_kernel<<<4096, 256, 0, stream>>>(HS_B, P_B, ln1_g + l * 1024, ln1_b + l * 1024);
    cvt_f2b<<<4096, 256, 0, stream>>>(ff1_w + (long long)l * 4194304, W1, 4194304);
    cvt_f2b<<<4096, 256, 0, stream>>>(ff2_w + (long long)l * 4194304, W2, 4194304);
    gemm_bt<<<dim3(32, 32, 1), 256, 0, stream>>>(
        HS_B, 1024, 0, 0, W1, 1024, 0, 0,
        FF1G, 4096, 0, 0, ff1_b + l * 4096, 1, 1, 32, nullptr);
    // FF2 (split-K S=2, nk=64)
    gemm_bt<<<dim3(8, 32, 2), 256, 0, stream>>>(
        FF1G, 4096, 0, 0, W2, 4096, 0, 0,
        P_B, 1024, 4194304, 0, nullptr, 0, 1, 64, PART_G);
    reduce_bias<<<4096, 256, 0, stream>>>(PART_G, 4194304, 2, ff2_b + l * 1024, 1024, P_B, 4194304LL);
    ln_kernel<<<4096, 256, 0, stream>>>(HS_B, P_B, ln2_g + l * 1024, ln2_b + l * 1024);
  }

  // ---- CNN decoder --------------------------------------------------------
  hipMemsetAsync((void*)ZPG, 0, 4096, stream);
  repack_w<<<512, 256, 0, stream>>>(dwv[0], WR1, 512, 10);
  repack_w<<<256, 256, 0, stream>>>(dwv[1], WR2, 256, 9);
  repack_w<<<128, 256, 0, stream>>>(dwv[2], WR3, 128, 8);
  repack_w<<<128, 256, 0, stream>>>(dwv[3], WR4, 64, 7);

  // conv1: split-K S=4 (1024 blocks, 4/CU), partial [4][4096][512] f32
  conv_gemm<3, 10, 72, 3><<<dim3(32, 8, 4), 256, 0, stream>>>(
      HS_B, WR1, C1, gv[0], bev[0], mv[0], vv[0], dbv[0], ZPG,
      512, PARTC1, 2097152);
  reduce_bn<<<2048, 256, 0, stream>>>(PARTC1, 2097152, 4,
      gv[0], bev[0], mv[0], vv[0], dbv[0], 512, C1, 2097152LL);
  ups2x<<<4096, 256, 0, stream>>>(C1, U1, 3, 3, 9, 1048576LL);
  // conv2: split-K S=2 (1024 blocks), partial [2][16384][256] f32
  conv_gemm<4, 9, 72, 3><<<dim3(128, 4, 2), 256, 0, stream>>>(
      U1, WR2, C2, gv[1], bev[1], mv[1], vv[1], dbv[1], ZPG,
      256, PARTC2, 4194304);
  reduce_bn<<<4096, 256, 0, stream>>>(PARTC2, 4194304, 2,
      gv[1], bev[1], mv[1], vv[1], dbv[1], 256, C2, 4194304LL);
  ups2x<<<8192, 256, 0, stream>>>(C2, U2, 4, 4, 8, 2097152LL);
  conv_gemm<5, 8, 72, 3><<<dim3(512, 2, 1), 256, 0, stream>>>(
      U2, WR3, C3, gv[2], bev[2], mv[2], vv[2], dbv[2], ZPG,
      128, nullptr, 0);
  ups2x<<<16384, 256, 0, stream>>>(C3, U3, 5, 5, 7, 4194304LL);
  // conv4: grid-rich (2048 blocks = 8/CU) -> BUFS=2 (24 KB LDS, 6 resident)
  conv_gemm<6, 7, 36, 2><<<dim3(2048, 1, 1), 256, 0, stream>>>(
      U3, WR4, C4, gv[3], bev[3], mv[3], vv[3], dbv[3], ZPG,
      64, nullptr, 0);
  conv1x1_final<<<65536, 256, 0, stream>>>(C4, dw5, db5, Z);
  ups_final<<<4096, 256, 0, stream>>>(Z, outp);
}